// Round 4
// baseline (989.624 us; speedup 1.0000x reference)
//
#include <hip/hip_runtime.h>

// ---------------------------------------------------------------------------
// Transformer-XL decoder layer on MI355X (gfx950).
// QLEN=1024, MLEN=1024, KLEN=2048, BSZ=4, DMODEL=1024, NHEAD=16, DHEAD=64, DFF=4096
// Round 10: attention v9 -- 8 blocks/CU (32 waves/CU), 2048 blocks ALL
// co-resident (v7's drift can't happen). Block (bn, y) owns i-tiles
// {y, 63-y} (constant 25-trip total); wave pair {0,1} splits tile A's
// j-range even/odd 128-chunks (stride 256), pair {2,3} tile B. Fixed-max
// softmax => partial O/l just add; one LDS exchange + single barrier.
// Main j-loop is byte-identical to v6/v8 (64 VGPR). v8 post-mortem: balance
// permutation was neutral -> the wall is latency at 4 waves/SIMD; this
// doubles TLP. L2 demand ~41 B/cyc/CU < 56 ceiling.
// rel_shift fact: BD[i,j] = BDu[i, j+1023-i] for j <= i+1024; rest is masked.
// ---------------------------------------------------------------------------

typedef __bf16 bf16x8 __attribute__((ext_vector_type(8)));
typedef float f32x4 __attribute__((ext_vector_type(4)));

#define DEVI __device__ __forceinline__

DEVI unsigned short f2bf(float f) {
  union { float f; unsigned int u; } v;
  v.f = f;
  unsigned int u = v.u;
  u += 0x7fffu + ((u >> 16) & 1u);  // RNE
  return (unsigned short)(u >> 16);
}

// async global->LDS, 16 B per lane; lds dest is the wave-uniform base.
DEVI void load16(const unsigned short* g, unsigned short* l) {
  __builtin_amdgcn_global_load_lds(
      (const __attribute__((address_space(1))) unsigned int*)g,
      (__attribute__((address_space(3))) unsigned int*)l, 16, 0, 0);
}

// ---------------------------------------------------------------------------
// f32 -> bf16 elementwise convert (grid covers exactly n/4 float4 groups)
// ---------------------------------------------------------------------------
__global__ __launch_bounds__(256) void cvt_bf16_kernel(const float* __restrict__ in,
                                                       unsigned short* __restrict__ out) {
  const int i = blockIdx.x * 256 + threadIdx.x;
  float4 v = *(const float4*)(in + (size_t)i * 4);
  ushort4 o;
  o.x = f2bf(v.x);
  o.y = f2bf(v.y);
  o.z = f2bf(v.z);
  o.w = f2bf(v.w);
  *(ushort4*)(out + (size_t)i * 4) = o;
}

// ---------------------------------------------------------------------------
// transpose + convert to bf16: out[c][r] = bf16(in[r][c])
// ---------------------------------------------------------------------------
template <typename T>
__global__ __launch_bounds__(256) void transpose_to_bf16(
    const T* __restrict__ in, unsigned short* __restrict__ out, int R, int C) {
  __shared__ unsigned short t[64][72];
  const int tid = threadIdx.x;
  const size_t zoff = (size_t)blockIdx.z * R * C;
  const int r0 = blockIdx.y * 64, c0 = blockIdx.x * 64;
  const T* inp = in + zoff;
  unsigned short* outp = out + zoff;
#pragma unroll
  for (int it = 0; it < 4; ++it) {
    int f = tid + 256 * it;
    int r = f >> 4;
    int c4 = (f & 15) << 2;
    if constexpr (sizeof(T) == 4) {
      float4 v = *(const float4*)((const float*)inp + (size_t)(r0 + r) * C + c0 + c4);
      t[c4 + 0][r] = f2bf(v.x);
      t[c4 + 1][r] = f2bf(v.y);
      t[c4 + 2][r] = f2bf(v.z);
      t[c4 + 3][r] = f2bf(v.w);
    } else {
      ushort4 v = *(const ushort4*)((const unsigned short*)inp + (size_t)(r0 + r) * C + c0 + c4);
      t[c4 + 0][r] = v.x;
      t[c4 + 1][r] = v.y;
      t[c4 + 2][r] = v.z;
      t[c4 + 3][r] = v.w;
    }
  }
  __syncthreads();
#pragma unroll
  for (int it = 0; it < 4; ++it) {
    int f = tid + 256 * it;
    int cc = f >> 4;
    int r4 = (f & 15) << 2;
    ushort4 o;
    o.x = t[cc][r4 + 0];
    o.y = t[cc][r4 + 1];
    o.z = t[cc][r4 + 2];
    o.w = t[cc][r4 + 3];
    *(ushort4*)(outp + (size_t)(c0 + cc) * R + r0 + r4) = o;
  }
}

// ---------------------------------------------------------------------------
// 128x128x64 MFMA GEMM, global_load_lds staging (unchanged from R3).
// EPI 0: QKV scatter (K/V to fragment-major); EPI 1: R scatter (frag-major);
// EPI 2: bias/resid/relu -> f32/bf16.
// Fragment-major layout (per 64-row slab, stride 131072 shorts):
//   AC/BD-type: idx = (t16*2+half)*512 + (quad*16+l15)*8 + e
//               value = X[row=t16*16+l15][col=half*32+quad*8+e]
//   PV-type V:  idx = jt*8192 + (ks*4+nto)*512 + (quad*16+l15)*8 + e
//               value = V[j=jt*128+ks*32+quad*8+e][d=nto*16+l15]
// ---------------------------------------------------------------------------
struct GemmArgs {
  const unsigned short* A;   // bf16 [M][K]
  const unsigned short* Bt;  // bf16 [N][K]
  int row_split;             // EPI0: rows below this skip q columns
  int M, N, K;
  const float* p0;  // bias_q (EPI0) / bias (EPI2)
  const float* p1;  // bias_k (EPI0)
  const float* resid;
  float* outF;
  unsigned short* o0;  // QQ / Rf / bf16-out
  unsigned short* o1;  // QK
  unsigned short* o2;  // Kf
  unsigned short* o3;  // Vf
  int relu;
};

constexpr int BM = 128, BN = 128, BK = 64;

template <int EPI>
__global__ __launch_bounds__(256, 4) void gemm_kernel(GemmArgs ga) {
  __shared__ __align__(16) unsigned short As[BM * BK];
  __shared__ __align__(16) unsigned short Bs[BN * BK];

  const int n0 = blockIdx.x * BN;
  const int m0 = blockIdx.y * BM;
  if constexpr (EPI == 0) {
    if (n0 + BN <= 1024 && m0 + BM <= ga.row_split) return;
  }
  const int tid = threadIdx.x;
  const int lane = tid & 63;
  const int wv = tid >> 6;
  const int l15 = lane & 15;
  const int quad = lane >> 4;
  const int wm = wv & 1, wn = wv >> 1;
  const int K = ga.K;
  const int r8 = lane >> 3;
  const int sc = (lane & 7) ^ r8;

  const f32x4 fzero = {0.f, 0.f, 0.f, 0.f};
  f32x4 acc[4][4];
#pragma unroll
  for (int i = 0; i < 4; ++i)
#pragma unroll
    for (int j = 0; j < 4; ++j) acc[i][j] = fzero;

  const unsigned short* Ab = ga.A + (size_t)(m0 + 32 * wv + r8) * K + sc * 8;
  const unsigned short* Bb = ga.Bt + (size_t)(n0 + 32 * wv + r8) * K + sc * 8;
  const int h7 = l15 & 7;

  for (int k0 = 0; k0 < K; k0 += BK) {
    __syncthreads();
#pragma unroll
    for (int it = 0; it < 4; ++it)
      load16(Ab + (size_t)(8 * it) * K + k0, &As[(32 * wv + 8 * it) * 64]);
#pragma unroll
    for (int it = 0; it < 4; ++it)
      load16(Bb + (size_t)(8 * it) * K + k0, &Bs[(32 * wv + 8 * it) * 64]);
    __syncthreads();
#pragma unroll
    for (int ks = 0; ks < 2; ++ks) {
      bf16x8 af[4], bg[4];
#pragma unroll
      for (int mt = 0; mt < 4; ++mt)
        af[mt] = *(const bf16x8*)&As[(wm * 64 + mt * 16 + l15) * 64 +
                                     (((ks * 4 + quad) ^ h7) * 8)];
#pragma unroll
      for (int nt = 0; nt < 4; ++nt)
        bg[nt] = *(const bf16x8*)&Bs[(wn * 64 + nt * 16 + l15) * 64 +
                                     (((ks * 4 + quad) ^ h7) * 8)];
#pragma unroll
      for (int mt = 0; mt < 4; ++mt)
#pragma unroll
        for (int nt = 0; nt < 4; ++nt)
          acc[mt][nt] =
              __builtin_amdgcn_mfma_f32_16x16x32_bf16(af[mt], bg[nt], acc[mt][nt], 0, 0, 0);
    }
  }

#pragma unroll
  for (int mt = 0; mt < 4; ++mt) {
#pragma unroll
    for (int nt = 0; nt < 4; ++nt) {
#pragma unroll
      for (int r = 0; r < 4; ++r) {
        const int row = m0 + wm * 64 + mt * 16 + quad * 4 + r;
        const int col = n0 + wn * 64 + nt * 16 + l15;
        float val = acc[mt][nt][r];
        if constexpr (EPI == 0) {
          const int seq = row >> 2, b = row & 3;  // cat flat row = seq*BSZ + b
          if (col < 1024) {
            if (seq >= 1024) {
              const int nh = col >> 6, d = col & 63;
              const size_t o = ((size_t)((b * 16 + nh) * 1024 + (seq - 1024))) * 64 + d;
              ga.o0[o] = f2bf(val + ga.p0[col]);  // q + bias_q
              ga.o1[o] = f2bf(val + ga.p1[col]);  // q + bias_k
            }
          } else if (col < 2048) {
            // K -> fragment-major
            const int c = col - 1024, nh = c >> 6, d = c & 63, bn = b * 16 + nh;
            const size_t o = (size_t)bn * 131072 +
                             (size_t)(((seq >> 4) * 2 + (d >> 5)) * 512) +
                             ((((d >> 3) & 3) * 16 + (seq & 15)) * 8) + (d & 7);
            ga.o2[o] = f2bf(val);
          } else {
            // V -> fragment-major (PV-type)
            const int c = col - 2048, nh = c >> 6, d = c & 63, bn = b * 16 + nh;
            const size_t o = (size_t)bn * 131072 + (size_t)((seq >> 7) * 8192) +
                             ((((seq >> 5) & 3) * 4 + (d >> 4)) * 512) +
                             ((((seq >> 3) & 3) * 16 + (d & 15)) * 8) + (seq & 7);
            ga.o3[o] = f2bf(val);
          }
        } else if constexpr (EPI == 1) {
          // R -> fragment-major per head
          const int nh = col >> 6, d = col & 63, t = row;
          const size_t o = (size_t)nh * 131072 +
                           (size_t)(((t >> 4) * 2 + (d >> 5)) * 512) +
                           ((((d >> 3) & 3) * 16 + (t & 15)) * 8) + (d & 7);
          ga.o0[o] = f2bf(val);
        } else {
          if (ga.p0) val += ga.p0[col];
          if (ga.resid) val += ga.resid[(size_t)row * ga.N + col];
          if (ga.relu) val = fmaxf(val, 0.f);
          if (ga.outF) ga.outF[(size_t)row * ga.N + col] = val;
          if (ga.o0) ga.o0[(size_t)row * ga.N + col] = f2bf(val);
        }
      }
    }
  }
}

// ---------------------------------------------------------------------------
// Flash attention with Transformer-XL relative-position term (v9).
// 8 blocks/CU, 2048 blocks all resident. Block (bn,y): wave pair {0,1} works
// i-tile y (j-chunks interleaved even/odd), pair {2,3} i-tile 63-y. Fixed-max
// softmax; partial O/l combined via one LDS exchange + single barrier.
// Main loop identical to v6/v8 (64 VGPR).
// ---------------------------------------------------------------------------
constexpr int P_LD = 136;            // p_s row stride (bf16 elems)
constexpr float CEXP = 0.18033688f;  // 0.125 * log2(e)

__global__ __launch_bounds__(256, 8) void attn_kernel(
    const unsigned short* __restrict__ QQ, const unsigned short* __restrict__ QK,
    const unsigned short* __restrict__ Kf, const unsigned short* __restrict__ Vf,
    const unsigned short* __restrict__ Rf, unsigned short* __restrict__ AVb) {
  __shared__ __align__(16) unsigned short p_s[4][16 * P_LD];

  const int tid = threadIdx.x;
  const int lane = tid & 63;
  const int wv = tid >> 6;
  const int l15 = lane & 15;
  const int quad = lane >> 4;
  const int bn = blockIdx.x;            // (b,n): block%8 == bn%8 -> XCD locality
  const int y = blockIdx.y;             // 0..31
  const int itl = (wv < 2) ? y : 63 - y;  // pair's i-tile; T_A+T_B = 25 const
  const int iw = itl * 16;
  const int ph = wv & 1;                // j-phase within the pair
  const int nh = bn & 15;
  const int bb = bn >> 4;
  unsigned short* pw = &p_s[wv][0];

  const unsigned short* kf = Kf + (size_t)bn * 131072;
  const unsigned short* vf = Vf + (size_t)bn * 131072;
  const unsigned short* rf = Rf + (size_t)nh * 131072;

  // Q fragments in registers: rows [iw, iw+16)
  const size_t qoff = (size_t)bn * (1024 * 64) + (size_t)(iw + l15) * 64;
  const bf16x8 qq0 = *(const bf16x8*)(QQ + qoff + quad * 8);
  const bf16x8 qq1 = *(const bf16x8*)(QQ + qoff + 32 + quad * 8);
  const bf16x8 qk0 = *(const bf16x8*)(QK + qoff + quad * 8);
  const bf16x8 qk1 = *(const bf16x8*)(QK + qoff + 32 + quad * 8);

  const f32x4 fzero = {0.f, 0.f, 0.f, 0.f};
  f32x4 o_acc[4];
#pragma unroll
  for (int i = 0; i < 4; ++i) o_acc[i] = fzero;
  float lsum[4] = {0.f, 0.f, 0.f, 0.f};

  const int lane8 = lane * 8;
  const int jmax = iw + 15 + 1024;  // beyond this, tiles are fully masked
  for (int j0 = ph * 128; j0 <= jmax; j0 += 256) {
    // BDu: window base t16b = (j0 + 1008 - iw)/16; 9 fragment tiles, clamped
    const int t16b = (j0 >> 4) + 63 - (iw >> 4);
    f32x4 bd[9];
#pragma unroll
    for (int ct = 0; ct < 9; ++ct) {
      int tg = t16b + ct;
      tg = (tg < 127) ? tg : 127;  // rows >=2048 only feed masked cols
      const unsigned short* rb = rf + (size_t)(tg * 1024) + lane8;
      bf16x8 b0 = *(const bf16x8*)rb;
      bf16x8 b1 = *(const bf16x8*)(rb + 512);
      f32x4 c = fzero;
      c = __builtin_amdgcn_mfma_f32_16x16x32_bf16(qk0, b0, c, 0, 0, 0);
      c = __builtin_amdgcn_mfma_f32_16x16x32_bf16(qk1, b1, c, 0, 0, 0);
      bd[ct] = c;
    }

    // AC = (q+bias_q) @ K^T
    const int ntb = j0 >> 4;
    f32x4 sv[8];
#pragma unroll
    for (int nt = 0; nt < 8; ++nt) {
      const unsigned short* kb = kf + (size_t)((ntb + nt) * 1024) + lane8;
      bf16x8 b0 = *(const bf16x8*)kb;
      bf16x8 b1 = *(const bf16x8*)(kb + 512);
      f32x4 c = fzero;
      c = __builtin_amdgcn_mfma_f32_16x16x32_bf16(qq0, b0, c, 0, 0, 0);
      c = __builtin_amdgcn_mfma_f32_16x16x32_bf16(qq1, b1, c, 0, 0, 0);
      sv[nt] = c;
    }

    // rel-shift (in-quad rotate) + fixed-max exp + per-lane l accumulation
#pragma unroll
    for (int r = 0; r < 4; ++r) {
      const int il = quad * 4 + r;  // tile-local row
      const int u = l15 + 15 - il;  // 0..30
      const int srcl = (lane & 48) | (u & 15);
      float w[9];
#pragma unroll
      for (int ct = 0; ct < 9; ++ct) w[ct] = __shfl(bd[ct][r], srcl, 64);
      const int ig = iw + il;
#pragma unroll
      for (int nt = 0; nt < 8; ++nt) {
        const float bdv = (u & 16) ? w[nt + 1] : w[nt];
        const int jg = j0 + nt * 16 + l15;
        float p = exp2f((sv[nt][r] + bdv) * CEXP);
        p = (jg > ig + 1024) ? 0.f : p;  // select: garbage/NaN-safe
        lsum[r] += p;
        pw[il * P_LD + nt * 16 + l15] = f2bf(p);
      }
    }

    // O += P @ V (K-dim = 128); V fragments coalesced from global
    const unsigned short* vb = vf + (size_t)((j0 >> 7) * 8192) + lane8;
#pragma unroll
    for (int ks = 0; ks < 4; ++ks) {
      bf16x8 ap = *(const bf16x8*)&pw[l15 * P_LD + ks * 32 + quad * 8];
#pragma unroll
      for (int nto = 0; nto < 4; ++nto) {
        bf16x8 bv = *(const bf16x8*)(vb + (ks * 4 + nto) * 512);
        o_acc[nto] = __builtin_amdgcn_mfma_f32_16x16x32_bf16(ap, bv, o_acc[nto], 0, 0, 0);
      }
    }
  }

  // reduce l across the 16 lanes holding each row (partial for this wave)
  float lred[4];
#pragma unroll
  for (int r = 0; r < 4; ++r) {
    float l = lsum[r];
    l += __shfl_xor(l, 1, 64);
    l += __shfl_xor(l, 2, 64);
    l += __shfl_xor(l, 4, 64);
    l += __shfl_xor(l, 8, 64);
    lred[r] = l;
  }

  // pairwise combine: odd wave publishes its partial O/l in its own p_s
  // region (row stride 67 floats to spread banks; 16*67+16 = 1088 floats fits
  // the 2176-ushort region exactly).
  float* fb = (float*)&p_s[wv][0];
  if (ph) {
#pragma unroll
    for (int nto = 0; nto < 4; ++nto)
#pragma unroll
      for (int r = 0; r < 4; ++r)
        fb[(quad * 4 + r) * 67 + nto * 16 + l15] = o_acc[nto][r];
    if (l15 == 0) {
#pragma unroll
      for (int r = 0; r < 4; ++r) fb[1072 + quad * 4 + r] = lred[r];
    }
  }
  __syncthreads();
  if (!ph) {
    const float* fp = (const float*)&p_s[wv + 1][0];
    float linv[4];
#pragma unroll
    for (int r = 0; r < 4; ++r)
      linv[r] = 1.f / (lred[r] + fp[1072 + quad * 4 + r]);
#pragma unroll
    for (int nto = 0; nto < 4; ++nto) {
#pragma unroll
      for (int r = 0; r < 4; ++r) {
        const int ig = iw + quad * 4 + r;
        const int d = nto * 16 + l15;
        const float val =
            (o_acc[nto][r] + fp[(quad * 4 + r) * 67 + nto * 16 + l15]) * linv[r];
        AVb[(size_t)(ig * 4 + bb) * 1024 + nh * 64 + d] = f2bf(val);
      }
    }
  }
}

// ---------------------------------------------------------------------------
// LayerNorm over rows of 1024; optional f32 and bf16 outputs.
// ---------------------------------------------------------------------------
__global__ __launch_bounds__(256) void ln_kernel(const float* __restrict__ x,
                                                 const float* __restrict__ g,
                                                 const float* __restrict__ bta,
                                                 float* __restrict__ outF,
                                                 unsigned short* __restrict__ outB) {
  const int row = blockIdx.x;
  const int tid = threadIdx.x;
  const float* xr = x + (size_t)row * 1024;
  const float4 v = *(const float4*)(xr + tid * 4);
  float s = v.x + v.y + v.z + v.w;
  float ss = v.x * v.x + v.y * v.y + v.z * v.z + v.w * v.w;
#pragma unroll
  for (int off = 1; off < 64; off <<= 1) {
    s += __shfl_xor(s, off, 64);
    ss += __shfl_xor(ss, off, 64);
  }
  __shared__ float red[8];
  const int wv = tid >> 6;
  if ((tid & 63) == 0) {
    red[wv] = s;
    red[4 + wv] = ss;
  }
  __syncthreads();
  s = red[0] + red[1] + red[2] + red[3];
  ss = red[4] + red[5] + red[6] + red[7];
  const float mu = s * (1.f / 1024.f);
  const float var = ss * (1.f / 1024.f) - mu * mu;
  const float rs = rsqrtf(var + 1e-5f);
  const float vv[4] = {v.x, v.y, v.z, v.w};
#pragma unroll
  for (int u = 0; u < 4; ++u) {
    const int c = tid * 4 + u;
    const float y = (vv[u] - mu) * rs * g[c] + bta[c];
    if (outF) outF[(size_t)row * 1024 + c] = y;
    if (outB) outB[(size_t)row * 1024 + c] = f2bf(y);
  }
}

// ---------------------------------------------------------------------------
extern "C" void kernel_launch(void* const* d_in, const int* in_sizes, int n_in,
                              void* d_out, int out_size, void* d_ws, size_t ws_size,
                              hipStream_t stream) {
  (void)in_sizes; (void)n_in; (void)out_size; (void)ws_size;
  const float* word_embed = (const float*)d_in[0];
  const float* pos_embed = (const float*)d_in[1];
  const float* bias_q = (const float*)d_in[2];
  const float* bias_k = (const float*)d_in[3];
  const float* memories = (const float*)d_in[4];
  const float* W_qkv = (const float*)d_in[5];
  const float* W_r = (const float*)d_in[6];
  const float* W_o = (const float*)d_in[7];
  const float* ln1_g = (const float*)d_in[8];
  const float* ln1_b = (const float*)d_in[9];
  const float* W_ff1 = (const float*)d_in[10];
  const float* b_ff1 = (const float*)d_in[11];
  const float* W_ff2 = (const float*)d_in[12];
  const float* b_ff2 = (const float*)d_in[13];
  const float* ln2_g = (const float*)d_in[14];
  const float* ln2_b = (const float*)d_in[15];
  float* out = (float*)d_out;

  char* ws = (char*)d_ws;
  unsigned short* QQ = (unsigned short*)(ws + 0);           // 8 MB
  unsigned short* QK = (unsigned short*)(ws + 8388608);     // 8 MB
  unsigned short* Kf = (unsigned short*)(ws + 16777216);    // 16 MB (frag-major)
  unsigned short* Vf = (unsigned short*)(ws + 50331648);    // 16 MB (frag-major)
  unsigned short* Rf = (unsigned short*)(ws + 67108864);    // 4 MB (frag-major)
  unsigned short* AVb = (unsigned short*)(ws + 71303168);   // 8 MB
  float* X1 = (float*)(ws + 79691776);                      // 16 MB (also C2)
  float* OUT1 = (float*)(ws + 96468992);                    // 16 MB
  unsigned short* OUT1b = (unsigned short*)(ws + 113246208);  // 8 MB
  unsigned short* Wqkv_t = (unsigned short*)(ws + 121634816); // 6 MB
  unsigned short* Wr_t = (unsigned short*)(ws + 127926272);   // 2 MB
  unsigned short* Wo_t = (unsigned short*)(ws + 130023424);   // 2 MB
  unsigned short* Wff1_t = (unsigned short*)(ws + 132120576); // 8 MB
  unsigned short* Wff2_t = (unsigned short*)(ws + 140509184); // 8 MB
  unsigned short* Catb = (unsigned short*)(ws + 79691776);    // aliases X1
  unsigned short* Posb = (unsigned short*)(ws + 96468992);    // aliases OUT1
  unsigned short* H = (unsigned short*)(ws + 0);              // aliases QQ/QK/Kf
  float* C2 = X1;

  const dim3 blk(256);

  cvt_bf16_kernel<<<4096, blk, 0, stream>>>(memories, Catb);
  cvt_bf16_kernel<<<4096, blk, 0, stream>>>(word_embed, Catb + (size_t)4096 * 1024);
  cvt_bf16_kernel<<<2048, blk, 0, stream>>>(pos_embed, Posb);

  transpose_to_bf16<float><<<dim3(48, 16, 1), blk, 0, stream>>>(W_qkv, Wqkv_t, 1024, 3072);
  transpose_to_bf16<float><<<dim3(16, 16, 1), blk, 0, stream>>>(W_r, Wr_t, 1024, 1024);
  transpose_to_bf16<float><<<dim3(16, 16, 1), blk, 0, stream>>>(W_o, Wo_t, 1024, 1024);
  transpose_to_bf16<float><<<dim3(64, 16, 1), blk, 0, stream>>>(W_ff1, Wff1_t, 1024, 4096);
  transpose_to_bf16<float><<<dim3(16, 64, 1), blk, 0, stream>>>(W_ff2, Wff2_t, 4096, 1024);

  // QKV projection: M=8192, N=3072, K=1024; K/V scattered to fragment-major
  {
    GemmArgs a{};
    a.A = Catb;
    a.row_split = 4096;
    a.Bt = Wqkv_t;
    a.M = 8192; a.N = 3072; a.K = 1024;
    a.p0 = bias_q; a.p1 = bias_k;
    a.o0 = QQ; a.o1 = QK; a.o2 = Kf; a.o3 = Vf;
    gemm_kernel<0><<<dim3(24, 64), blk, 0, stream>>>(a);
  }
  // R projection: M=2048, N=1024, K=1024 -> fragment-major per head
  {
    GemmArgs a{};
    a.A = Posb;
    a.Bt = Wr_t;
    a.M = 2048; a.N = 1024; a.K = 1024;
    a.o0 = Rf;
    gemm_kernel<1><<<dim3(8, 16), blk, 0, stream>>>(a);
  }

  // attention: grid (bn=64, y=32), 2048 blocks, 8/CU, all co-resident
  attn_kernel<<<dim3(64, 32), blk, 0, stream>>>(QQ, QK, Kf, Vf, Rf, AVb);

  {
    GemmArgs a{};
    a.A = AVb;
    a.Bt = Wo_t;
    a.M = 4096; a.N = 1024; a.K = 1024;
    a.resid = word_embed;
    a.outF = X1;
    gemm_kernel<2><<<dim3(8, 32), blk, 0, stream>>>(a);
  }
  ln_kernel<<<4096, blk, 0, stream>>>(X1, ln1_g, ln1_b, OUT1, OUT1b);

  {
    GemmArgs a{};
    a.A = OUT1b;
    a.Bt = Wff1_t;
    a.M = 4096; a.N = 4096; a.K = 1024;
    a.p0 = b_ff1;
    a.relu = 1;
    a.o0 = H;
    gemm_kernel<2><<<dim3(32, 32), blk, 0, stream>>>(a);
  }
  {
    GemmArgs a{};
    a.A = H;
    a.Bt = Wff2_t;
    a.M = 4096; a.N = 1024; a.K = 4096;
    a.p0 = b_ff2;
    a.resid = OUT1;
    a.outF = C2;
    gemm_kernel<2><<<dim3(8, 32), blk, 0, stream>>>(a);
  }
  ln_kernel<<<4096, blk, 0, stream>>>(C2, ln2_g, ln2_b, out, nullptr);
}

// Round 5
// 776.462 us; speedup vs baseline: 1.2745x; 1.2745x over previous
//
#include <hip/hip_runtime.h>

// ---------------------------------------------------------------------------
// Transformer-XL decoder layer on MI355X (gfx950).
// QLEN=1024, MLEN=1024, KLEN=2048, BSZ=4, DMODEL=1024, NHEAD=16, DHEAD=64, DFF=4096
// Round 11: attention v10 = v7's 32-row-tile inner loop (0.52 loads/MFMA)
// inside v6's residency envelope (1024 blocks, 4/CU, block%8==bn%8 XCD
// locality). Block (bn,y) owns 32-row i-tiles {y, 31-y}; wave pair {0,1}
// splits tile A's j-range even/odd 128-chunks, pair {2,3} tile B. Fixed-max
// softmax partials add; one pairwise LDS exchange + single barrier (v9's
// combine, correctness-proven). v9 post-mortem: (256,8) halves the VGPR
// budget to 64 -> spills (VGPR 32, 1.7 GB scratch traffic). Occupancy is
// register-capped; this round raises ILP-per-load instead of TLP.
// rel_shift fact: BD[i,j] = BDu[i, j+1023-i] for j <= i+1024; rest is masked.
// ---------------------------------------------------------------------------

typedef __bf16 bf16x8 __attribute__((ext_vector_type(8)));
typedef float f32x4 __attribute__((ext_vector_type(4)));

#define DEVI __device__ __forceinline__

DEVI unsigned short f2bf(float f) {
  union { float f; unsigned int u; } v;
  v.f = f;
  unsigned int u = v.u;
  u += 0x7fffu + ((u >> 16) & 1u);  // RNE
  return (unsigned short)(u >> 16);
}

// async global->LDS, 16 B per lane; lds dest is the wave-uniform base.
DEVI void load16(const unsigned short* g, unsigned short* l) {
  __builtin_amdgcn_global_load_lds(
      (const __attribute__((address_space(1))) unsigned int*)g,
      (__attribute__((address_space(3))) unsigned int*)l, 16, 0, 0);
}

// ---------------------------------------------------------------------------
// f32 -> bf16 elementwise convert (grid covers exactly n/4 float4 groups)
// ---------------------------------------------------------------------------
__global__ __launch_bounds__(256) void cvt_bf16_kernel(const float* __restrict__ in,
                                                       unsigned short* __restrict__ out) {
  const int i = blockIdx.x * 256 + threadIdx.x;
  float4 v = *(const float4*)(in + (size_t)i * 4);
  ushort4 o;
  o.x = f2bf(v.x);
  o.y = f2bf(v.y);
  o.z = f2bf(v.z);
  o.w = f2bf(v.w);
  *(ushort4*)(out + (size_t)i * 4) = o;
}

// ---------------------------------------------------------------------------
// transpose + convert to bf16: out[c][r] = bf16(in[r][c])
// ---------------------------------------------------------------------------
template <typename T>
__global__ __launch_bounds__(256) void transpose_to_bf16(
    const T* __restrict__ in, unsigned short* __restrict__ out, int R, int C) {
  __shared__ unsigned short t[64][72];
  const int tid = threadIdx.x;
  const size_t zoff = (size_t)blockIdx.z * R * C;
  const int r0 = blockIdx.y * 64, c0 = blockIdx.x * 64;
  const T* inp = in + zoff;
  unsigned short* outp = out + zoff;
#pragma unroll
  for (int it = 0; it < 4; ++it) {
    int f = tid + 256 * it;
    int r = f >> 4;
    int c4 = (f & 15) << 2;
    if constexpr (sizeof(T) == 4) {
      float4 v = *(const float4*)((const float*)inp + (size_t)(r0 + r) * C + c0 + c4);
      t[c4 + 0][r] = f2bf(v.x);
      t[c4 + 1][r] = f2bf(v.y);
      t[c4 + 2][r] = f2bf(v.z);
      t[c4 + 3][r] = f2bf(v.w);
    } else {
      ushort4 v = *(const ushort4*)((const unsigned short*)inp + (size_t)(r0 + r) * C + c0 + c4);
      t[c4 + 0][r] = v.x;
      t[c4 + 1][r] = v.y;
      t[c4 + 2][r] = v.z;
      t[c4 + 3][r] = v.w;
    }
  }
  __syncthreads();
#pragma unroll
  for (int it = 0; it < 4; ++it) {
    int f = tid + 256 * it;
    int cc = f >> 4;
    int r4 = (f & 15) << 2;
    ushort4 o;
    o.x = t[cc][r4 + 0];
    o.y = t[cc][r4 + 1];
    o.z = t[cc][r4 + 2];
    o.w = t[cc][r4 + 3];
    *(ushort4*)(outp + (size_t)(c0 + cc) * R + r0 + r4) = o;
  }
}

// ---------------------------------------------------------------------------
// 128x128x64 MFMA GEMM, global_load_lds staging (unchanged from R3).
// EPI 0: QKV scatter (K/V to fragment-major); EPI 1: R scatter (frag-major);
// EPI 2: bias/resid/relu -> f32/bf16.
// Fragment-major layout (per 64-row slab, stride 131072 shorts):
//   AC/BD-type: idx = (t16*2+half)*512 + (quad*16+l15)*8 + e
//               value = X[row=t16*16+l15][col=half*32+quad*8+e]
//   PV-type V:  idx = jt*8192 + (ks*4+nto)*512 + (quad*16+l15)*8 + e
//               value = V[j=jt*128+ks*32+quad*8+e][d=nto*16+l15]
// ---------------------------------------------------------------------------
struct GemmArgs {
  const unsigned short* A;   // bf16 [M][K]
  const unsigned short* Bt;  // bf16 [N][K]
  int row_split;             // EPI0: rows below this skip q columns
  int M, N, K;
  const float* p0;  // bias_q (EPI0) / bias (EPI2)
  const float* p1;  // bias_k (EPI0)
  const float* resid;
  float* outF;
  unsigned short* o0;  // QQ / Rf / bf16-out
  unsigned short* o1;  // QK
  unsigned short* o2;  // Kf
  unsigned short* o3;  // Vf
  int relu;
};

constexpr int BM = 128, BN = 128, BK = 64;

template <int EPI>
__global__ __launch_bounds__(256, 4) void gemm_kernel(GemmArgs ga) {
  __shared__ __align__(16) unsigned short As[BM * BK];
  __shared__ __align__(16) unsigned short Bs[BN * BK];

  const int n0 = blockIdx.x * BN;
  const int m0 = blockIdx.y * BM;
  if constexpr (EPI == 0) {
    if (n0 + BN <= 1024 && m0 + BM <= ga.row_split) return;
  }
  const int tid = threadIdx.x;
  const int lane = tid & 63;
  const int wv = tid >> 6;
  const int l15 = lane & 15;
  const int quad = lane >> 4;
  const int wm = wv & 1, wn = wv >> 1;
  const int K = ga.K;
  const int r8 = lane >> 3;
  const int sc = (lane & 7) ^ r8;

  const f32x4 fzero = {0.f, 0.f, 0.f, 0.f};
  f32x4 acc[4][4];
#pragma unroll
  for (int i = 0; i < 4; ++i)
#pragma unroll
    for (int j = 0; j < 4; ++j) acc[i][j] = fzero;

  const unsigned short* Ab = ga.A + (size_t)(m0 + 32 * wv + r8) * K + sc * 8;
  const unsigned short* Bb = ga.Bt + (size_t)(n0 + 32 * wv + r8) * K + sc * 8;
  const int h7 = l15 & 7;

  for (int k0 = 0; k0 < K; k0 += BK) {
    __syncthreads();
#pragma unroll
    for (int it = 0; it < 4; ++it)
      load16(Ab + (size_t)(8 * it) * K + k0, &As[(32 * wv + 8 * it) * 64]);
#pragma unroll
    for (int it = 0; it < 4; ++it)
      load16(Bb + (size_t)(8 * it) * K + k0, &Bs[(32 * wv + 8 * it) * 64]);
    __syncthreads();
#pragma unroll
    for (int ks = 0; ks < 2; ++ks) {
      bf16x8 af[4], bg[4];
#pragma unroll
      for (int mt = 0; mt < 4; ++mt)
        af[mt] = *(const bf16x8*)&As[(wm * 64 + mt * 16 + l15) * 64 +
                                     (((ks * 4 + quad) ^ h7) * 8)];
#pragma unroll
      for (int nt = 0; nt < 4; ++nt)
        bg[nt] = *(const bf16x8*)&Bs[(wn * 64 + nt * 16 + l15) * 64 +
                                     (((ks * 4 + quad) ^ h7) * 8)];
#pragma unroll
      for (int mt = 0; mt < 4; ++mt)
#pragma unroll
        for (int nt = 0; nt < 4; ++nt)
          acc[mt][nt] =
              __builtin_amdgcn_mfma_f32_16x16x32_bf16(af[mt], bg[nt], acc[mt][nt], 0, 0, 0);
    }
  }

#pragma unroll
  for (int mt = 0; mt < 4; ++mt) {
#pragma unroll
    for (int nt = 0; nt < 4; ++nt) {
#pragma unroll
      for (int r = 0; r < 4; ++r) {
        const int row = m0 + wm * 64 + mt * 16 + quad * 4 + r;
        const int col = n0 + wn * 64 + nt * 16 + l15;
        float val = acc[mt][nt][r];
        if constexpr (EPI == 0) {
          const int seq = row >> 2, b = row & 3;  // cat flat row = seq*BSZ + b
          if (col < 1024) {
            if (seq >= 1024) {
              const int nh = col >> 6, d = col & 63;
              const size_t o = ((size_t)((b * 16 + nh) * 1024 + (seq - 1024))) * 64 + d;
              ga.o0[o] = f2bf(val + ga.p0[col]);  // q + bias_q
              ga.o1[o] = f2bf(val + ga.p1[col]);  // q + bias_k
            }
          } else if (col < 2048) {
            // K -> fragment-major
            const int c = col - 1024, nh = c >> 6, d = c & 63, bn = b * 16 + nh;
            const size_t o = (size_t)bn * 131072 +
                             (size_t)(((seq >> 4) * 2 + (d >> 5)) * 512) +
                             ((((d >> 3) & 3) * 16 + (seq & 15)) * 8) + (d & 7);
            ga.o2[o] = f2bf(val);
          } else {
            // V -> fragment-major (PV-type)
            const int c = col - 2048, nh = c >> 6, d = c & 63, bn = b * 16 + nh;
            const size_t o = (size_t)bn * 131072 + (size_t)((seq >> 7) * 8192) +
                             ((((seq >> 5) & 3) * 4 + (d >> 4)) * 512) +
                             ((((seq >> 3) & 3) * 16 + (d & 15)) * 8) + (seq & 7);
            ga.o3[o] = f2bf(val);
          }
        } else if constexpr (EPI == 1) {
          // R -> fragment-major per head
          const int nh = col >> 6, d = col & 63, t = row;
          const size_t o = (size_t)nh * 131072 +
                           (size_t)(((t >> 4) * 2 + (d >> 5)) * 512) +
                           ((((d >> 3) & 3) * 16 + (t & 15)) * 8) + (d & 7);
          ga.o0[o] = f2bf(val);
        } else {
          if (ga.p0) val += ga.p0[col];
          if (ga.resid) val += ga.resid[(size_t)row * ga.N + col];
          if (ga.relu) val = fmaxf(val, 0.f);
          if (ga.outF) ga.outF[(size_t)row * ga.N + col] = val;
          if (ga.o0) ga.o0[(size_t)row * ga.N + col] = f2bf(val);
        }
      }
    }
  }
}

// ---------------------------------------------------------------------------
// Flash attention with Transformer-XL relative-position term (v10).
// 1024 blocks (64 bn x 16 y), 4 blocks/CU, all co-resident, XCD-aligned.
// Block owns 32-row tiles {y, 31-y}; wave pair {0,1} -> tile A (j even/odd),
// pair {2,3} -> tile B. Per-wave inner loop = v7's chunked 32-row math
// (R/K/V fragments shared across halves; V shared in PV). Fixed-max softmax;
// pairwise LDS combine + single barrier at epilogue.
// ---------------------------------------------------------------------------
constexpr int P_LD = 136;            // p row stride (bf16 elems)
constexpr float CEXP = 0.18033688f;  // 0.125 * log2(e)

__global__ __launch_bounds__(256, 4) void attn_kernel(
    const unsigned short* __restrict__ QQ, const unsigned short* __restrict__ QK,
    const unsigned short* __restrict__ Kf, const unsigned short* __restrict__ Vf,
    const unsigned short* __restrict__ Rf, unsigned short* __restrict__ AVb) {
  // [4 waves][32 rows][P_LD] bf16 P-tiles; per-wave region (2176 f32) also
  // holds the odd wave's partial O (32x67) + l (32) for the epilogue combine.
  __shared__ __align__(16) unsigned short p_s[4][32 * P_LD];

  const int tid = threadIdx.x;
  const int lane = tid & 63;
  const int wv = tid >> 6;
  const int l15 = lane & 15;
  const int quad = lane >> 4;
  const int bn = blockIdx.x;              // (b,n): block%8 == bn%8 -> XCD locality
  const int y = blockIdx.y;               // 0..15
  const int itl = (wv < 2) ? y : 31 - y;  // pair's 32-row i-tile
  const int ib = itl * 32;
  const int ph = wv & 1;                  // j-phase within the pair
  const int nh = bn & 15;
  const int bb = bn >> 4;
  unsigned short* pw = &p_s[wv][0];

  const unsigned short* kf = Kf + (size_t)bn * 131072;
  const unsigned short* vf = Vf + (size_t)bn * 131072;
  const unsigned short* rf = Rf + (size_t)nh * 131072;

  // Q fragments for both 16-row halves
  bf16x8 qq[2][2], qk[2][2];
#pragma unroll
  for (int h = 0; h < 2; ++h) {
    const size_t qoff = (size_t)bn * (1024 * 64) + (size_t)(ib + 16 * h + l15) * 64;
    qq[h][0] = *(const bf16x8*)(QQ + qoff + quad * 8);
    qq[h][1] = *(const bf16x8*)(QQ + qoff + 32 + quad * 8);
    qk[h][0] = *(const bf16x8*)(QK + qoff + quad * 8);
    qk[h][1] = *(const bf16x8*)(QK + qoff + 32 + quad * 8);
  }

  const f32x4 fzero = {0.f, 0.f, 0.f, 0.f};
  f32x4 o_acc[2][4];
#pragma unroll
  for (int h = 0; h < 2; ++h)
#pragma unroll
    for (int i = 0; i < 4; ++i) o_acc[h][i] = fzero;
  float lsum[2][4] = {{0.f, 0.f, 0.f, 0.f}, {0.f, 0.f, 0.f, 0.f}};

  const int lane8 = lane * 8;
  const int jmax = ib + 31 + 1024;  // beyond this, tiles are fully masked
  for (int j0 = ph * 128; j0 <= jmax; j0 += 256) {
    const int ntb = j0 >> 4;
#pragma unroll
    for (int h = 0; h < 2; ++h) {
      const int ih = ib + 16 * h;
      const int t16b = ntb + 63 - (ih >> 4);
      // ---- chunk A: bd tiles 0..4, sv cols 0..3, softmax nt 0..3 ----
      f32x4 bd[5];
#pragma unroll
      for (int ct = 0; ct < 5; ++ct) {
        int tg = t16b + ct;
        tg = (tg < 127) ? tg : 127;  // rows >=2048 only feed masked cols
        const unsigned short* rb = rf + (size_t)(tg * 1024) + lane8;
        bf16x8 b0 = *(const bf16x8*)rb;
        bf16x8 b1 = *(const bf16x8*)(rb + 512);
        f32x4 c = fzero;
        c = __builtin_amdgcn_mfma_f32_16x16x32_bf16(qk[h][0], b0, c, 0, 0, 0);
        c = __builtin_amdgcn_mfma_f32_16x16x32_bf16(qk[h][1], b1, c, 0, 0, 0);
        bd[ct] = c;
      }
      f32x4 sv[4];
#pragma unroll
      for (int nt = 0; nt < 4; ++nt) {
        const unsigned short* kb = kf + (size_t)((ntb + nt) * 1024) + lane8;
        bf16x8 b0 = *(const bf16x8*)kb;
        bf16x8 b1 = *(const bf16x8*)(kb + 512);
        f32x4 c = fzero;
        c = __builtin_amdgcn_mfma_f32_16x16x32_bf16(qq[h][0], b0, c, 0, 0, 0);
        c = __builtin_amdgcn_mfma_f32_16x16x32_bf16(qq[h][1], b1, c, 0, 0, 0);
        sv[nt] = c;
      }
#pragma unroll
      for (int r = 0; r < 4; ++r) {
        const int il = quad * 4 + r;  // half-local row
        const int u = l15 + 15 - il;  // 0..30
        const int srcl = (lane & 48) | (u & 15);
        float w[5];
#pragma unroll
        for (int ct = 0; ct < 5; ++ct) w[ct] = __shfl(bd[ct][r], srcl, 64);
        const int ig = ih + il;
#pragma unroll
        for (int nt = 0; nt < 4; ++nt) {
          const float bdv = (u & 16) ? w[nt + 1] : w[nt];
          const int jg = j0 + nt * 16 + l15;
          float p = exp2f((sv[nt][r] + bdv) * CEXP);
          p = (jg > ig + 1024) ? 0.f : p;  // select: garbage/NaN-safe
          lsum[h][r] += p;
          pw[(h * 16 + il) * P_LD + nt * 16 + l15] = f2bf(p);
        }
      }
      // ---- chunk B: bd tiles 4..8 (tile4 carried), sv cols 4..7 ----
      f32x4 bdB[5];
      bdB[0] = bd[4];
#pragma unroll
      for (int ct = 1; ct < 5; ++ct) {
        int tg = t16b + 4 + ct;
        tg = (tg < 127) ? tg : 127;
        const unsigned short* rb = rf + (size_t)(tg * 1024) + lane8;
        bf16x8 b0 = *(const bf16x8*)rb;
        bf16x8 b1 = *(const bf16x8*)(rb + 512);
        f32x4 c = fzero;
        c = __builtin_amdgcn_mfma_f32_16x16x32_bf16(qk[h][0], b0, c, 0, 0, 0);
        c = __builtin_amdgcn_mfma_f32_16x16x32_bf16(qk[h][1], b1, c, 0, 0, 0);
        bdB[ct] = c;
      }
#pragma unroll
      for (int nt = 0; nt < 4; ++nt) {
        const unsigned short* kb = kf + (size_t)((ntb + nt + 4) * 1024) + lane8;
        bf16x8 b0 = *(const bf16x8*)kb;
        bf16x8 b1 = *(const bf16x8*)(kb + 512);
        f32x4 c = fzero;
        c = __builtin_amdgcn_mfma_f32_16x16x32_bf16(qq[h][0], b0, c, 0, 0, 0);
        c = __builtin_amdgcn_mfma_f32_16x16x32_bf16(qq[h][1], b1, c, 0, 0, 0);
        sv[nt] = c;
      }
#pragma unroll
      for (int r = 0; r < 4; ++r) {
        const int il = quad * 4 + r;
        const int u = l15 + 15 - il;
        const int srcl = (lane & 48) | (u & 15);
        float w[5];
#pragma unroll
        for (int ct = 0; ct < 5; ++ct) w[ct] = __shfl(bdB[ct][r], srcl, 64);
        const int ig = ih + il;
#pragma unroll
        for (int nt = 0; nt < 4; ++nt) {
          const float bdv = (u & 16) ? w[nt + 1] : w[nt];
          const int jg = j0 + (nt + 4) * 16 + l15;
          float p = exp2f((sv[nt][r] + bdv) * CEXP);
          p = (jg > ig + 1024) ? 0.f : p;
          lsum[h][r] += p;
          pw[(h * 16 + il) * P_LD + (nt + 4) * 16 + l15] = f2bf(p);
        }
      }
    }

    // O += P @ V (K-dim = 128); V fragments shared by both halves
    const unsigned short* vb = vf + (size_t)((j0 >> 7) * 8192) + lane8;
#pragma unroll
    for (int ks = 0; ks < 4; ++ks) {
      bf16x8 ap0 = *(const bf16x8*)&pw[l15 * P_LD + ks * 32 + quad * 8];
      bf16x8 ap1 = *(const bf16x8*)&pw[(16 + l15) * P_LD + ks * 32 + quad * 8];
#pragma unroll
      for (int nto = 0; nto < 4; ++nto) {
        bf16x8 bv = *(const bf16x8*)(vb + (ks * 4 + nto) * 512);
        o_acc[0][nto] = __builtin_amdgcn_mfma_f32_16x16x32_bf16(ap0, bv, o_acc[0][nto], 0, 0, 0);
        o_acc[1][nto] = __builtin_amdgcn_mfma_f32_16x16x32_bf16(ap1, bv, o_acc[1][nto], 0, 0, 0);
      }
    }
  }

  // reduce l across the 16 lanes holding each row (partial for this wave)
  float lred[2][4];
#pragma unroll
  for (int h = 0; h < 2; ++h) {
#pragma unroll
    for (int r = 0; r < 4; ++r) {
      float l = lsum[h][r];
      l += __shfl_xor(l, 1, 64);
      l += __shfl_xor(l, 2, 64);
      l += __shfl_xor(l, 4, 64);
      l += __shfl_xor(l, 8, 64);
      lred[h][r] = l;
    }
  }

  // pairwise combine: odd wave publishes partial O (32x67 f32) + l (32 f32)
  // in its own p_s region (32*67+32 = 2176 f32 = exact region size).
  float* fb = (float*)&p_s[wv][0];
  if (ph) {
#pragma unroll
    for (int h = 0; h < 2; ++h)
#pragma unroll
      for (int nto = 0; nto < 4; ++nto)
#pragma unroll
        for (int r = 0; r < 4; ++r)
          fb[(h * 16 + quad * 4 + r) * 67 + nto * 16 + l15] = o_acc[h][nto][r];
    if (l15 == 0) {
#pragma unroll
      for (int h = 0; h < 2; ++h)
#pragma unroll
        for (int r = 0; r < 4; ++r) fb[2144 + h * 16 + quad * 4 + r] = lred[h][r];
    }
  }
  __syncthreads();
  if (!ph) {
    const float* fp = (const float*)&p_s[wv + 1][0];
#pragma unroll
    for (int h = 0; h < 2; ++h) {
      float linv[4];
#pragma unroll
      for (int r = 0; r < 4; ++r)
        linv[r] = 1.f / (lred[h][r] + fp[2144 + h * 16 + quad * 4 + r]);
#pragma unroll
      for (int nto = 0; nto < 4; ++nto) {
#pragma unroll
        for (int r = 0; r < 4; ++r) {
          const int ig = ib + h * 16 + quad * 4 + r;
          const int d = nto * 16 + l15;
          const float val =
              (o_acc[h][nto][r] + fp[(h * 16 + quad * 4 + r) * 67 + nto * 16 + l15]) *
              linv[r];
          AVb[(size_t)(ig * 4 + bb) * 1024 + nh * 64 + d] = f2bf(val);
        }
      }
    }
  }
}

// ---------------------------------------------------------------------------
// LayerNorm over rows of 1024; optional f32 and bf16 outputs.
// ---------------------------------------------------------------------------
__global__ __launch_bounds__(256) void ln_kernel(const float* __restrict__ x,
                                                 const float* __restrict__ g,
                                                 const float* __restrict__ bta,
                                                 float* __restrict__ outF,
                                                 unsigned short* __restrict__ outB) {
  const int row = blockIdx.x;
  const int tid = threadIdx.x;
  const float* xr = x + (size_t)row * 1024;
  const float4 v = *(const float4*)(xr + tid * 4);
  float s = v.x + v.y + v.z + v.w;
  float ss = v.x * v.x + v.y * v.y + v.z * v.z + v.w * v.w;
#pragma unroll
  for (int off = 1; off < 64; off <<= 1) {
    s += __shfl_xor(s, off, 64);
    ss += __shfl_xor(ss, off, 64);
  }
  __shared__ float red[8];
  const int wv = tid >> 6;
  if ((tid & 63) == 0) {
    red[wv] = s;
    red[4 + wv] = ss;
  }
  __syncthreads();
  s = red[0] + red[1] + red[2] + red[3];
  ss = red[4] + red[5] + red[6] + red[7];
  const float mu = s * (1.f / 1024.f);
  const float var = ss * (1.f / 1024.f) - mu * mu;
  const float rs = rsqrtf(var + 1e-5f);
  const float vv[4] = {v.x, v.y, v.z, v.w};
#pragma unroll
  for (int u = 0; u < 4; ++u) {
    const int c = tid * 4 + u;
    const float y = (vv[u] - mu) * rs * g[c] + bta[c];
    if (outF) outF[(size_t)row * 1024 + c] = y;
    if (outB) outB[(size_t)row * 1024 + c] = f2bf(y);
  }
}

// ---------------------------------------------------------------------------
extern "C" void kernel_launch(void* const* d_in, const int* in_sizes, int n_in,
                              void* d_out, int out_size, void* d_ws, size_t ws_size,
                              hipStream_t stream) {
  (void)in_sizes; (void)n_in; (void)out_size; (void)ws_size;
  const float* word_embed = (const float*)d_in[0];
  const float* pos_embed = (const float*)d_in[1];
  const float* bias_q = (const float*)d_in[2];
  const float* bias_k = (const float*)d_in[3];
  const float* memories = (const float*)d_in[4];
  const float* W_qkv = (const float*)d_in[5];
  const float* W_r = (const float*)d_in[6];
  const float* W_o = (const float*)d_in[7];
  const float* ln1_g = (const float*)d_in[8];
  const float* ln1_b = (const float*)d_in[9];
  const float* W_ff1 = (const float*)d_in[10];
  const float* b_ff1 = (const float*)d_in[11];
  const float* W_ff2 = (const float*)d_in[12];
  const float* b_ff2 = (const float*)d_in[13];
  const float* ln2_g = (const float*)d_in[14];
  const float* ln2_b = (const float*)d_in[15];
  float* out = (float*)d_out;

  char* ws = (char*)d_ws;
  unsigned short* QQ = (unsigned short*)(ws + 0);           // 8 MB
  unsigned short* QK = (unsigned short*)(ws + 8388608);     // 8 MB
  unsigned short* Kf = (unsigned short*)(ws + 16777216);    // 16 MB (frag-major)
  unsigned short* Vf = (unsigned short*)(ws + 50331648);    // 16 MB (frag-major)
  unsigned short* Rf = (unsigned short*)(ws + 67108864);    // 4 MB (frag-major)
  unsigned short* AVb = (unsigned short*)(ws + 71303168);   // 8 MB
  float* X1 = (float*)(ws + 79691776);                      // 16 MB (also C2)
  float* OUT1 = (float*)(ws + 96468992);                    // 16 MB
  unsigned short* OUT1b = (unsigned short*)(ws + 113246208);  // 8 MB
  unsigned short* Wqkv_t = (unsigned short*)(ws + 121634816); // 6 MB
  unsigned short* Wr_t = (unsigned short*)(ws + 127926272);   // 2 MB
  unsigned short* Wo_t = (unsigned short*)(ws + 130023424);   // 2 MB
  unsigned short* Wff1_t = (unsigned short*)(ws + 132120576); // 8 MB
  unsigned short* Wff2_t = (unsigned short*)(ws + 140509184); // 8 MB
  unsigned short* Catb = (unsigned short*)(ws + 79691776);    // aliases X1
  unsigned short* Posb = (unsigned short*)(ws + 96468992);    // aliases OUT1
  unsigned short* H = (unsigned short*)(ws + 0);              // aliases QQ/QK/Kf
  float* C2 = X1;

  const dim3 blk(256);

  cvt_bf16_kernel<<<4096, blk, 0, stream>>>(memories, Catb);
  cvt_bf16_kernel<<<4096, blk, 0, stream>>>(word_embed, Catb + (size_t)4096 * 1024);
  cvt_bf16_kernel<<<2048, blk, 0, stream>>>(pos_embed, Posb);

  transpose_to_bf16<float><<<dim3(48, 16, 1), blk, 0, stream>>>(W_qkv, Wqkv_t, 1024, 3072);
  transpose_to_bf16<float><<<dim3(16, 16, 1), blk, 0, stream>>>(W_r, Wr_t, 1024, 1024);
  transpose_to_bf16<float><<<dim3(16, 16, 1), blk, 0, stream>>>(W_o, Wo_t, 1024, 1024);
  transpose_to_bf16<float><<<dim3(64, 16, 1), blk, 0, stream>>>(W_ff1, Wff1_t, 1024, 4096);
  transpose_to_bf16<float><<<dim3(16, 64, 1), blk, 0, stream>>>(W_ff2, Wff2_t, 4096, 1024);

  // QKV projection: M=8192, N=3072, K=1024; K/V scattered to fragment-major
  {
    GemmArgs a{};
    a.A = Catb;
    a.row_split = 4096;
    a.Bt = Wqkv_t;
    a.M = 8192; a.N = 3072; a.K = 1024;
    a.p0 = bias_q; a.p1 = bias_k;
    a.o0 = QQ; a.o1 = QK; a.o2 = Kf; a.o3 = Vf;
    gemm_kernel<0><<<dim3(24, 64), blk, 0, stream>>>(a);
  }
  // R projection: M=2048, N=1024, K=1024 -> fragment-major per head
  {
    GemmArgs a{};
    a.A = Posb;
    a.Bt = Wr_t;
    a.M = 2048; a.N = 1024; a.K = 1024;
    a.o0 = Rf;
    gemm_kernel<1><<<dim3(8, 16), blk, 0, stream>>>(a);
  }

  // attention: grid (bn=64, y=16), 1024 blocks, 4/CU, XCD-aligned, pairs
  attn_kernel<<<dim3(64, 16), blk, 0, stream>>>(QQ, QK, Kf, Vf, Rf, AVb);

  {
    GemmArgs a{};
    a.A = AVb;
    a.Bt = Wo_t;
    a.M = 4096; a.N = 1024; a.K = 1024;
    a.resid = word_embed;
    a.outF = X1;
    gemm_kernel<2><<<dim3(8, 32), blk, 0, stream>>>(a);
  }
  ln_kernel<<<4096, blk, 0, stream>>>(X1, ln1_g, ln1_b, OUT1, OUT1b);

  {
    GemmArgs a{};
    a.A = OUT1b;
    a.Bt = Wff1_t;
    a.M = 4096; a.N = 4096; a.K = 1024;
    a.p0 = b_ff1;
    a.relu = 1;
    a.o0 = H;
    gemm_kernel<2><<<dim3(32, 32), blk, 0, stream>>>(a);
  }
  {
    GemmArgs a{};
    a.A = H;
    a.Bt = Wff2_t;
    a.M = 4096; a.N = 1024; a.K = 4096;
    a.p0 = b_ff2;
    a.resid = OUT1;
    a.outF = C2;
    gemm_kernel<2><<<dim3(8, 32), blk, 0, stream>>>(a);
  }
  ln_kernel<<<4096, blk, 0, stream>>>(C2, ln2_g, ln2_b, out, nullptr);
}

// Round 6
// 724.281 us; speedup vs baseline: 1.3664x; 1.0720x over previous
//
#include <hip/hip_runtime.h>

// ---------------------------------------------------------------------------
// Transformer-XL decoder layer on MI355X (gfx950).
// QLEN=1024, MLEN=1024, KLEN=2048, BSZ=4, DMODEL=1024, NHEAD=16, DHEAD=64, DFF=4096
// Round 12: attn = round-0 v6 (proven 214 us) + s_setprio around MFMA
// clusters (T5). GEMM side: WN=2 (128x64) variant for Wo/FF2/R-proj
// (256/256/128 -> 512/512/256 blocks, 2x residency), and QKV uses a flat
// 1280-block active-tile enumeration (exactly 5/CU, no dead blocks, no
// ragged tail; 16 consecutive blocks share an A-panel).
// v7/v10 post-mortem recorded: attn waves within a block MUST scan the same
// j-chunk together (L1/L2 reuse); de-synchronized j-streams thrash -> 8x
// fabric traffic. v6's consecutive i-tile mapping also shares the R window.
// rel_shift fact: BD[i,j] = BDu[i, j+1023-i] for j <= i+1024; rest is masked.
// ---------------------------------------------------------------------------

typedef __bf16 bf16x8 __attribute__((ext_vector_type(8)));
typedef float f32x4 __attribute__((ext_vector_type(4)));

#define DEVI __device__ __forceinline__

DEVI unsigned short f2bf(float f) {
  union { float f; unsigned int u; } v;
  v.f = f;
  unsigned int u = v.u;
  u += 0x7fffu + ((u >> 16) & 1u);  // RNE
  return (unsigned short)(u >> 16);
}

// async global->LDS, 16 B per lane; lds dest is the wave-uniform base.
DEVI void load16(const unsigned short* g, unsigned short* l) {
  __builtin_amdgcn_global_load_lds(
      (const __attribute__((address_space(1))) unsigned int*)g,
      (__attribute__((address_space(3))) unsigned int*)l, 16, 0, 0);
}

// ---------------------------------------------------------------------------
// f32 -> bf16 elementwise convert (grid covers exactly n/4 float4 groups)
// ---------------------------------------------------------------------------
__global__ __launch_bounds__(256) void cvt_bf16_kernel(const float* __restrict__ in,
                                                       unsigned short* __restrict__ out) {
  const int i = blockIdx.x * 256 + threadIdx.x;
  float4 v = *(const float4*)(in + (size_t)i * 4);
  ushort4 o;
  o.x = f2bf(v.x);
  o.y = f2bf(v.y);
  o.z = f2bf(v.z);
  o.w = f2bf(v.w);
  *(ushort4*)(out + (size_t)i * 4) = o;
}

// ---------------------------------------------------------------------------
// transpose + convert to bf16: out[c][r] = bf16(in[r][c])
// ---------------------------------------------------------------------------
template <typename T>
__global__ __launch_bounds__(256) void transpose_to_bf16(
    const T* __restrict__ in, unsigned short* __restrict__ out, int R, int C) {
  __shared__ unsigned short t[64][72];
  const int tid = threadIdx.x;
  const size_t zoff = (size_t)blockIdx.z * R * C;
  const int r0 = blockIdx.y * 64, c0 = blockIdx.x * 64;
  const T* inp = in + zoff;
  unsigned short* outp = out + zoff;
#pragma unroll
  for (int it = 0; it < 4; ++it) {
    int f = tid + 256 * it;
    int r = f >> 4;
    int c4 = (f & 15) << 2;
    if constexpr (sizeof(T) == 4) {
      float4 v = *(const float4*)((const float*)inp + (size_t)(r0 + r) * C + c0 + c4);
      t[c4 + 0][r] = f2bf(v.x);
      t[c4 + 1][r] = f2bf(v.y);
      t[c4 + 2][r] = f2bf(v.z);
      t[c4 + 3][r] = f2bf(v.w);
    } else {
      ushort4 v = *(const ushort4*)((const unsigned short*)inp + (size_t)(r0 + r) * C + c0 + c4);
      t[c4 + 0][r] = v.x;
      t[c4 + 1][r] = v.y;
      t[c4 + 2][r] = v.z;
      t[c4 + 3][r] = v.w;
    }
  }
  __syncthreads();
#pragma unroll
  for (int it = 0; it < 4; ++it) {
    int f = tid + 256 * it;
    int cc = f >> 4;
    int r4 = (f & 15) << 2;
    ushort4 o;
    o.x = t[cc][r4 + 0];
    o.y = t[cc][r4 + 1];
    o.z = t[cc][r4 + 2];
    o.w = t[cc][r4 + 3];
    *(ushort4*)(outp + (size_t)(c0 + cc) * R + r0 + r4) = o;
  }
}

// ---------------------------------------------------------------------------
// 128xBN x64 MFMA GEMM, global_load_lds staging. WN=4 -> BN=128 (proven
// path, byte-identical); WN=2 -> BN=64 for small-N GEMMs (2x block count).
// EPI 0: QKV scatter (K/V to fragment-major), flat 1280-block active grid;
// EPI 1: R scatter (frag-major); EPI 2: bias/resid/relu -> f32/bf16.
// Fragment-major layout (per 64-row slab, stride 131072 shorts):
//   AC/BD-type: idx = (t16*2+half)*512 + (quad*16+l15)*8 + e
//               value = X[row=t16*16+l15][col=half*32+quad*8+e]
//   PV-type V:  idx = jt*8192 + (ks*4+nto)*512 + (quad*16+l15)*8 + e
//               value = V[j=jt*128+ks*32+quad*8+e][d=nto*16+l15]
// ---------------------------------------------------------------------------
struct GemmArgs {
  const unsigned short* A;   // bf16 [M][K]
  const unsigned short* Bt;  // bf16 [N][K]
  int row_split;             // (unused; kept for ABI stability)
  int M, N, K;
  const float* p0;  // bias_q (EPI0) / bias (EPI2)
  const float* p1;  // bias_k (EPI0)
  const float* resid;
  float* outF;
  unsigned short* o0;  // QQ / Rf / bf16-out
  unsigned short* o1;  // QK
  unsigned short* o2;  // Kf
  unsigned short* o3;  // Vf
  int relu;
};

constexpr int BM = 128, BK = 64;

template <int EPI, int WN = 4>
__global__ __launch_bounds__(256, 4) void gemm_kernel(GemmArgs ga) {
  constexpr int BN_ = WN * 32;
  __shared__ __align__(16) unsigned short As[BM * BK];
  __shared__ __align__(16) unsigned short Bs[BN_ * BK];

  int m0, n0;
  if constexpr (EPI == 0) {
    // flat enumeration of the 1280 active tiles (skip q-cols x memory-rows)
    const int flat = blockIdx.x;
    int mt_, nt_;
    if (flat < 1024) {         // K/V columns: ntile 8..23, all 64 m-tiles
      mt_ = flat >> 4;
      nt_ = 8 + (flat & 15);
    } else {                   // q columns: ntile 0..7, m-tiles 32..63
      const int f2 = flat - 1024;
      mt_ = 32 + (f2 >> 3);
      nt_ = f2 & 7;
    }
    m0 = mt_ * 128;
    n0 = nt_ * 128;
  } else {
    n0 = blockIdx.x * BN_;
    m0 = blockIdx.y * BM;
  }
  const int tid = threadIdx.x;
  const int lane = tid & 63;
  const int wv = tid >> 6;
  const int l15 = lane & 15;
  const int quad = lane >> 4;
  const int wm = wv & 1, wn = wv >> 1;
  const int K = ga.K;
  const int r8 = lane >> 3;
  const int sc = (lane & 7) ^ r8;

  const f32x4 fzero = {0.f, 0.f, 0.f, 0.f};
  f32x4 acc[4][WN];
#pragma unroll
  for (int i = 0; i < 4; ++i)
#pragma unroll
    for (int j = 0; j < WN; ++j) acc[i][j] = fzero;

  const unsigned short* Ab = ga.A + (size_t)(m0 + 32 * wv + r8) * K + sc * 8;
  const unsigned short* Bb = ga.Bt + (size_t)(n0 + (BN_ / 4) * wv + r8) * K + sc * 8;
  const int h7 = l15 & 7;

  for (int k0 = 0; k0 < K; k0 += BK) {
    __syncthreads();
#pragma unroll
    for (int it = 0; it < 4; ++it)
      load16(Ab + (size_t)(8 * it) * K + k0, &As[(32 * wv + 8 * it) * 64]);
#pragma unroll
    for (int it = 0; it < BN_ / 32; ++it)
      load16(Bb + (size_t)(8 * it) * K + k0, &Bs[((BN_ / 4) * wv + 8 * it) * 64]);
    __syncthreads();
#pragma unroll
    for (int ks = 0; ks < 2; ++ks) {
      bf16x8 af[4], bg[WN];
#pragma unroll
      for (int mt = 0; mt < 4; ++mt)
        af[mt] = *(const bf16x8*)&As[(wm * 64 + mt * 16 + l15) * 64 +
                                     (((ks * 4 + quad) ^ h7) * 8)];
#pragma unroll
      for (int nt = 0; nt < WN; ++nt)
        bg[nt] = *(const bf16x8*)&Bs[(wn * (WN * 16) + nt * 16 + l15) * 64 +
                                     (((ks * 4 + quad) ^ h7) * 8)];
#pragma unroll
      for (int mt = 0; mt < 4; ++mt)
#pragma unroll
        for (int nt = 0; nt < WN; ++nt)
          acc[mt][nt] =
              __builtin_amdgcn_mfma_f32_16x16x32_bf16(af[mt], bg[nt], acc[mt][nt], 0, 0, 0);
    }
  }

#pragma unroll
  for (int mt = 0; mt < 4; ++mt) {
#pragma unroll
    for (int nt = 0; nt < WN; ++nt) {
#pragma unroll
      for (int r = 0; r < 4; ++r) {
        const int row = m0 + wm * 64 + mt * 16 + quad * 4 + r;
        const int col = n0 + wn * (WN * 16) + nt * 16 + l15;
        float val = acc[mt][nt][r];
        if constexpr (EPI == 0) {
          const int seq = row >> 2, b = row & 3;  // cat flat row = seq*BSZ + b
          if (col < 1024) {
            if (seq >= 1024) {
              const int nh = col >> 6, d = col & 63;
              const size_t o = ((size_t)((b * 16 + nh) * 1024 + (seq - 1024))) * 64 + d;
              ga.o0[o] = f2bf(val + ga.p0[col]);  // q + bias_q
              ga.o1[o] = f2bf(val + ga.p1[col]);  // q + bias_k
            }
          } else if (col < 2048) {
            // K -> fragment-major
            const int c = col - 1024, nh = c >> 6, d = c & 63, bn = b * 16 + nh;
            const size_t o = (size_t)bn * 131072 +
                             (size_t)(((seq >> 4) * 2 + (d >> 5)) * 512) +
                             ((((d >> 3) & 3) * 16 + (seq & 15)) * 8) + (d & 7);
            ga.o2[o] = f2bf(val);
          } else {
            // V -> fragment-major (PV-type)
            const int c = col - 2048, nh = c >> 6, d = c & 63, bn = b * 16 + nh;
            const size_t o = (size_t)bn * 131072 + (size_t)((seq >> 7) * 8192) +
                             ((((seq >> 5) & 3) * 4 + (d >> 4)) * 512) +
                             ((((seq >> 3) & 3) * 16 + (d & 15)) * 8) + (seq & 7);
            ga.o3[o] = f2bf(val);
          }
        } else if constexpr (EPI == 1) {
          // R -> fragment-major per head
          const int nh = col >> 6, d = col & 63, t = row;
          const size_t o = (size_t)nh * 131072 +
                           (size_t)(((t >> 4) * 2 + (d >> 5)) * 512) +
                           ((((d >> 3) & 3) * 16 + (t & 15)) * 8) + (d & 7);
          ga.o0[o] = f2bf(val);
        } else {
          if (ga.p0) val += ga.p0[col];
          if (ga.resid) val += ga.resid[(size_t)row * ga.N + col];
          if (ga.relu) val = fmaxf(val, 0.f);
          if (ga.outF) ga.outF[(size_t)row * ga.N + col] = val;
          if (ga.o0) ga.o0[(size_t)row * ga.N + col] = f2bf(val);
        }
      }
    }
  }
}

// ---------------------------------------------------------------------------
// Flash attention with Transformer-XL relative-position term (v6 + setprio).
// Barrier-free; one wave per 16-row i-tile (consecutive tiles per block ->
// K/V AND R windows L1-shared across the block's lockstep waves); 4 blocks/CU;
// 1024 blocks exactly resident (block%8 == bn%8 -> XCD slab locality).
// Fixed-max softmax; l reduced once at epilogue; P hop via wave-private LDS.
// s_setprio(1) wraps the MFMA clusters (T5), prio 0 during softmax VALU.
// ---------------------------------------------------------------------------
constexpr int P_LD = 136;            // p_s row stride (bf16 elems)
constexpr float CEXP = 0.18033688f;  // 0.125 * log2(e)

__global__ __launch_bounds__(256, 4) void attn_kernel(
    const unsigned short* __restrict__ QQ, const unsigned short* __restrict__ QK,
    const unsigned short* __restrict__ Kf, const unsigned short* __restrict__ Vf,
    const unsigned short* __restrict__ Rf, unsigned short* __restrict__ AVb) {
  __shared__ __align__(16) unsigned short p_s[4][16 * P_LD];

  const int tid = threadIdx.x;
  const int lane = tid & 63;
  const int wv = tid >> 6;
  const int l15 = lane & 15;
  const int quad = lane >> 4;
  const int bn = blockIdx.x;                   // (b,n): block%8 == bn%8 -> XCD locality
  const int iw = (blockIdx.y * 4 + wv) * 16;   // wave-private 16-row i-tile
  const int nh = bn & 15;
  const int bb = bn >> 4;
  unsigned short* pw = &p_s[wv][0];

  const unsigned short* kf = Kf + (size_t)bn * 131072;
  const unsigned short* vf = Vf + (size_t)bn * 131072;
  const unsigned short* rf = Rf + (size_t)nh * 131072;

  // Q fragments in registers: rows [iw, iw+16)
  const size_t qoff = (size_t)bn * (1024 * 64) + (size_t)(iw + l15) * 64;
  const bf16x8 qq0 = *(const bf16x8*)(QQ + qoff + quad * 8);
  const bf16x8 qq1 = *(const bf16x8*)(QQ + qoff + 32 + quad * 8);
  const bf16x8 qk0 = *(const bf16x8*)(QK + qoff + quad * 8);
  const bf16x8 qk1 = *(const bf16x8*)(QK + qoff + 32 + quad * 8);

  const f32x4 fzero = {0.f, 0.f, 0.f, 0.f};
  f32x4 o_acc[4];
#pragma unroll
  for (int i = 0; i < 4; ++i) o_acc[i] = fzero;
  float lsum[4] = {0.f, 0.f, 0.f, 0.f};

  const int lane8 = lane * 8;
  const int jmax = iw + 15 + 1024;  // beyond this, tiles are fully masked
  for (int j0 = 0; j0 <= jmax; j0 += 128) {
    // BDu: window base t16b = (j0 + 1008 - iw)/16; 9 fragment tiles, clamped
    const int t16b = (j0 >> 4) + 63 - (iw >> 4);
    __builtin_amdgcn_s_setprio(1);
    f32x4 bd[9];
#pragma unroll
    for (int ct = 0; ct < 9; ++ct) {
      int tg = t16b + ct;
      tg = (tg < 127) ? tg : 127;  // rows >=2048 only feed masked cols
      const unsigned short* rb = rf + (size_t)(tg * 1024) + lane8;
      bf16x8 b0 = *(const bf16x8*)rb;
      bf16x8 b1 = *(const bf16x8*)(rb + 512);
      f32x4 c = fzero;
      c = __builtin_amdgcn_mfma_f32_16x16x32_bf16(qk0, b0, c, 0, 0, 0);
      c = __builtin_amdgcn_mfma_f32_16x16x32_bf16(qk1, b1, c, 0, 0, 0);
      bd[ct] = c;
    }

    // AC = (q+bias_q) @ K^T
    const int ntb = j0 >> 4;
    f32x4 sv[8];
#pragma unroll
    for (int nt = 0; nt < 8; ++nt) {
      const unsigned short* kb = kf + (size_t)((ntb + nt) * 1024) + lane8;
      bf16x8 b0 = *(const bf16x8*)kb;
      bf16x8 b1 = *(const bf16x8*)(kb + 512);
      f32x4 c = fzero;
      c = __builtin_amdgcn_mfma_f32_16x16x32_bf16(qq0, b0, c, 0, 0, 0);
      c = __builtin_amdgcn_mfma_f32_16x16x32_bf16(qq1, b1, c, 0, 0, 0);
      sv[nt] = c;
    }
    __builtin_amdgcn_s_setprio(0);

    // rel-shift (in-quad rotate) + fixed-max exp + per-lane l accumulation
#pragma unroll
    for (int r = 0; r < 4; ++r) {
      const int il = quad * 4 + r;  // tile-local row
      const int u = l15 + 15 - il;  // 0..30
      const int srcl = (lane & 48) | (u & 15);
      float w[9];
#pragma unroll
      for (int ct = 0; ct < 9; ++ct) w[ct] = __shfl(bd[ct][r], srcl, 64);
      const int ig = iw + il;
#pragma unroll
      for (int nt = 0; nt < 8; ++nt) {
        const float bdv = (u & 16) ? w[nt + 1] : w[nt];
        const int jg = j0 + nt * 16 + l15;
        float p = exp2f((sv[nt][r] + bdv) * CEXP);
        p = (jg > ig + 1024) ? 0.f : p;  // select: garbage/NaN-safe
        lsum[r] += p;
        pw[il * P_LD + nt * 16 + l15] = f2bf(p);
      }
    }

    // O += P @ V (K-dim = 128); V fragments coalesced from global
    const unsigned short* vb = vf + (size_t)((j0 >> 7) * 8192) + lane8;
    __builtin_amdgcn_s_setprio(1);
#pragma unroll
    for (int ks = 0; ks < 4; ++ks) {
      bf16x8 ap = *(const bf16x8*)&pw[l15 * P_LD + ks * 32 + quad * 8];
#pragma unroll
      for (int nto = 0; nto < 4; ++nto) {
        bf16x8 bv = *(const bf16x8*)(vb + (ks * 4 + nto) * 512);
        o_acc[nto] = __builtin_amdgcn_mfma_f32_16x16x32_bf16(ap, bv, o_acc[nto], 0, 0, 0);
      }
    }
    __builtin_amdgcn_s_setprio(0);
  }

  // reduce l across the 16 lanes holding each row, then write O/l
  float linv[4];
#pragma unroll
  for (int r = 0; r < 4; ++r) {
    float l = lsum[r];
    l += __shfl_xor(l, 1, 64);
    l += __shfl_xor(l, 2, 64);
    l += __shfl_xor(l, 4, 64);
    l += __shfl_xor(l, 8, 64);
    linv[r] = 1.f / l;
  }
#pragma unroll
  for (int nto = 0; nto < 4; ++nto) {
#pragma unroll
    for (int r = 0; r < 4; ++r) {
      const int ig = iw + quad * 4 + r;
      const int d = nto * 16 + l15;
      const float val = o_acc[nto][r] * linv[r];
      AVb[(size_t)(ig * 4 + bb) * 1024 + nh * 64 + d] = f2bf(val);
    }
  }
}

// ---------------------------------------------------------------------------
// LayerNorm over rows of 1024; optional f32 and bf16 outputs.
// ---------------------------------------------------------------------------
__global__ __launch_bounds__(256) void ln_kernel(const float* __restrict__ x,
                                                 const float* __restrict__ g,
                                                 const float* __restrict__ bta,
                                                 float* __restrict__ outF,
                                                 unsigned short* __restrict__ outB) {
  const int row = blockIdx.x;
  const int tid = threadIdx.x;
  const float* xr = x + (size_t)row * 1024;
  const float4 v = *(const float4*)(xr + tid * 4);
  float s = v.x + v.y + v.z + v.w;
  float ss = v.x * v.x + v.y * v.y + v.z * v.z + v.w * v.w;
#pragma unroll
  for (int off = 1; off < 64; off <<= 1) {
    s += __shfl_xor(s, off, 64);
    ss += __shfl_xor(ss, off, 64);
  }
  __shared__ float red[8];
  const int wv = tid >> 6;
  if ((tid & 63) == 0) {
    red[wv] = s;
    red[4 + wv] = ss;
  }
  __syncthreads();
  s = red[0] + red[1] + red[2] + red[3];
  ss = red[4] + red[5] + red[6] + red[7];
  const float mu = s * (1.f / 1024.f);
  const float var = ss * (1.f / 1024.f) - mu * mu;
  const float rs = rsqrtf(var + 1e-5f);
  const float vv[4] = {v.x, v.y, v.z, v.w};
#pragma unroll
  for (int u = 0; u < 4; ++u) {
    const int c = tid * 4 + u;
    const float y = (vv[u] - mu) * rs * g[c] + bta[c];
    if (outF) outF[(size_t)row * 1024 + c] = y;
    if (outB) outB[(size_t)row * 1024 + c] = f2bf(y);
  }
}

// ---------------------------------------------------------------------------
extern "C" void kernel_launch(void* const* d_in, const int* in_sizes, int n_in,
                              void* d_out, int out_size, void* d_ws, size_t ws_size,
                              hipStream_t stream) {
  (void)in_sizes; (void)n_in; (void)out_size; (void)ws_size;
  const float* word_embed = (const float*)d_in[0];
  const float* pos_embed = (const float*)d_in[1];
  const float* bias_q = (const float*)d_in[2];
  const float* bias_k = (const float*)d_in[3];
  const float* memories = (const float*)d_in[4];
  const float* W_qkv = (const float*)d_in[5];
  const float* W_r = (const float*)d_in[6];
  const float* W_o = (const float*)d_in[7];
  const float* ln1_g = (const float*)d_in[8];
  const float* ln1_b = (const float*)d_in[9];
  const float* W_ff1 = (const float*)d_in[10];
  const float* b_ff1 = (const float*)d_in[11];
  const float* W_ff2 = (const float*)d_in[12];
  const float* b_ff2 = (const float*)d_in[13];
  const float* ln2_g = (const float*)d_in[14];
  const float* ln2_b = (const float*)d_in[15];
  float* out = (float*)d_out;

  char* ws = (char*)d_ws;
  unsigned short* QQ = (unsigned short*)(ws + 0);           // 8 MB
  unsigned short* QK = (unsigned short*)(ws + 8388608);     // 8 MB
  unsigned short* Kf = (unsigned short*)(ws + 16777216);    // 16 MB (frag-major)
  unsigned short* Vf = (unsigned short*)(ws + 50331648);    // 16 MB (frag-major)
  unsigned short* Rf = (unsigned short*)(ws + 67108864);    // 4 MB (frag-major)
  unsigned short* AVb = (unsigned short*)(ws + 71303168);   // 8 MB
  float* X1 = (float*)(ws + 79691776);                      // 16 MB (also C2)
  float* OUT1 = (float*)(ws + 96468992);                    // 16 MB
  unsigned short* OUT1b = (unsigned short*)(ws + 113246208);  // 8 MB
  unsigned short* Wqkv_t = (unsigned short*)(ws + 121634816); // 6 MB
  unsigned short* Wr_t = (unsigned short*)(ws + 127926272);   // 2 MB
  unsigned short* Wo_t = (unsigned short*)(ws + 130023424);   // 2 MB
  unsigned short* Wff1_t = (unsigned short*)(ws + 132120576); // 8 MB
  unsigned short* Wff2_t = (unsigned short*)(ws + 140509184); // 8 MB
  unsigned short* Catb = (unsigned short*)(ws + 79691776);    // aliases X1
  unsigned short* Posb = (unsigned short*)(ws + 96468992);    // aliases OUT1
  unsigned short* H = (unsigned short*)(ws + 0);              // aliases QQ/QK/Kf
  float* C2 = X1;

  const dim3 blk(256);

  cvt_bf16_kernel<<<4096, blk, 0, stream>>>(memories, Catb);
  cvt_bf16_kernel<<<4096, blk, 0, stream>>>(word_embed, Catb + (size_t)4096 * 1024);
  cvt_bf16_kernel<<<2048, blk, 0, stream>>>(pos_embed, Posb);

  transpose_to_bf16<float><<<dim3(48, 16, 1), blk, 0, stream>>>(W_qkv, Wqkv_t, 1024, 3072);
  transpose_to_bf16<float><<<dim3(16, 16, 1), blk, 0, stream>>>(W_r, Wr_t, 1024, 1024);
  transpose_to_bf16<float><<<dim3(16, 16, 1), blk, 0, stream>>>(W_o, Wo_t, 1024, 1024);
  transpose_to_bf16<float><<<dim3(64, 16, 1), blk, 0, stream>>>(W_ff1, Wff1_t, 1024, 4096);
  transpose_to_bf16<float><<<dim3(16, 64, 1), blk, 0, stream>>>(W_ff2, Wff2_t, 4096, 1024);

  // QKV projection: M=8192, N=3072, K=1024; flat 1280-block active grid
  {
    GemmArgs a{};
    a.A = Catb;
    a.Bt = Wqkv_t;
    a.M = 8192; a.N = 3072; a.K = 1024;
    a.p0 = bias_q; a.p1 = bias_k;
    a.o0 = QQ; a.o1 = QK; a.o2 = Kf; a.o3 = Vf;
    gemm_kernel<0><<<dim3(1280), blk, 0, stream>>>(a);
  }
  // R projection: M=2048, N=1024, K=1024 -> fragment-major per head (BN=64)
  {
    GemmArgs a{};
    a.A = Posb;
    a.Bt = Wr_t;
    a.M = 2048; a.N = 1024; a.K = 1024;
    a.o0 = Rf;
    gemm_kernel<1, 2><<<dim3(16, 16), blk, 0, stream>>>(a);
  }

  // attention: grid (bn=64, itile=16), 1024 blocks, 4/CU, barrier-free
  attn_kernel<<<dim3(64, 16), blk, 0, stream>>>(QQ, QK, Kf, Vf, Rf, AVb);

  // W_o projection (BN=64 -> 512 blocks, 2/CU)
  {
    GemmArgs a{};
    a.A = AVb;
    a.Bt = Wo_t;
    a.M = 4096; a.N = 1024; a.K = 1024;
    a.resid = word_embed;
    a.outF = X1;
    gemm_kernel<2, 2><<<dim3(16, 32), blk, 0, stream>>>(a);
  }
  ln_kernel<<<4096, blk, 0, stream>>>(X1, ln1_g, ln1_b, OUT1, OUT1b);

  // FF1 (BN=128, 1024 blocks)
  {
    GemmArgs a{};
    a.A = OUT1b;
    a.Bt = Wff1_t;
    a.M = 4096; a.N = 4096; a.K = 1024;
    a.p0 = b_ff1;
    a.relu = 1;
    a.o0 = H;
    gemm_kernel<2><<<dim3(32, 32), blk, 0, stream>>>(a);
  }
  // FF2 (BN=64 -> 512 blocks, 2/CU)
  {
    GemmArgs a{};
    a.A = H;
    a.Bt = Wff2_t;
    a.M = 4096; a.N = 1024; a.K = 4096;
    a.p0 = b_ff2;
    a.resid = OUT1;
    a.outF = C2;
    gemm_kernel<2, 2><<<dim3(16, 32), blk, 0, stream>>>(a);
  }
  ln_kernel<<<4096, blk, 0, stream>>>(C2, ln2_g, ln2_b, out, nullptr);
}

// Round 7
// 653.489 us; speedup vs baseline: 1.5144x; 1.1083x over previous
//
#include <hip/hip_runtime.h>

// ---------------------------------------------------------------------------
// Transformer-XL decoder layer on MI355X (gfx950).
// QLEN=1024, MLEN=1024, KLEN=2048, BSZ=4, DMODEL=1024, NHEAD=16, DHEAD=64, DFF=4096
// Round 13: attn = byte-exact round-0 v6 (214 us proven). setprio REMOVED:
// it de-synchronized the block's lockstep waves -> L1 thrash (FETCH 30->210,
// WRITE 69->382 MB, dur +37%). Lesson: this attn's perf rests on the 4 waves
// sharing L1 lines of the same j-chunk; ANY arbitration/ordering change that
// skews their j-positions re-streams K/V from fabric.
// GEMM side keeps round-12 wins (~30 us): flat 1280-block QKV active-tile
// grid; WN=2 (128x64) tiles for R-proj/Wo/FF2 (2x block residency).
// rel_shift fact: BD[i,j] = BDu[i, j+1023-i] for j <= i+1024; rest is masked.
// ---------------------------------------------------------------------------

typedef __bf16 bf16x8 __attribute__((ext_vector_type(8)));
typedef float f32x4 __attribute__((ext_vector_type(4)));

#define DEVI __device__ __forceinline__

DEVI unsigned short f2bf(float f) {
  union { float f; unsigned int u; } v;
  v.f = f;
  unsigned int u = v.u;
  u += 0x7fffu + ((u >> 16) & 1u);  // RNE
  return (unsigned short)(u >> 16);
}

// async global->LDS, 16 B per lane; lds dest is the wave-uniform base.
DEVI void load16(const unsigned short* g, unsigned short* l) {
  __builtin_amdgcn_global_load_lds(
      (const __attribute__((address_space(1))) unsigned int*)g,
      (__attribute__((address_space(3))) unsigned int*)l, 16, 0, 0);
}

// ---------------------------------------------------------------------------
// f32 -> bf16 elementwise convert (grid covers exactly n/4 float4 groups)
// ---------------------------------------------------------------------------
__global__ __launch_bounds__(256) void cvt_bf16_kernel(const float* __restrict__ in,
                                                       unsigned short* __restrict__ out) {
  const int i = blockIdx.x * 256 + threadIdx.x;
  float4 v = *(const float4*)(in + (size_t)i * 4);
  ushort4 o;
  o.x = f2bf(v.x);
  o.y = f2bf(v.y);
  o.z = f2bf(v.z);
  o.w = f2bf(v.w);
  *(ushort4*)(out + (size_t)i * 4) = o;
}

// ---------------------------------------------------------------------------
// transpose + convert to bf16: out[c][r] = bf16(in[r][c])
// ---------------------------------------------------------------------------
template <typename T>
__global__ __launch_bounds__(256) void transpose_to_bf16(
    const T* __restrict__ in, unsigned short* __restrict__ out, int R, int C) {
  __shared__ unsigned short t[64][72];
  const int tid = threadIdx.x;
  const size_t zoff = (size_t)blockIdx.z * R * C;
  const int r0 = blockIdx.y * 64, c0 = blockIdx.x * 64;
  const T* inp = in + zoff;
  unsigned short* outp = out + zoff;
#pragma unroll
  for (int it = 0; it < 4; ++it) {
    int f = tid + 256 * it;
    int r = f >> 4;
    int c4 = (f & 15) << 2;
    if constexpr (sizeof(T) == 4) {
      float4 v = *(const float4*)((const float*)inp + (size_t)(r0 + r) * C + c0 + c4);
      t[c4 + 0][r] = f2bf(v.x);
      t[c4 + 1][r] = f2bf(v.y);
      t[c4 + 2][r] = f2bf(v.z);
      t[c4 + 3][r] = f2bf(v.w);
    } else {
      ushort4 v = *(const ushort4*)((const unsigned short*)inp + (size_t)(r0 + r) * C + c0 + c4);
      t[c4 + 0][r] = v.x;
      t[c4 + 1][r] = v.y;
      t[c4 + 2][r] = v.z;
      t[c4 + 3][r] = v.w;
    }
  }
  __syncthreads();
#pragma unroll
  for (int it = 0; it < 4; ++it) {
    int f = tid + 256 * it;
    int cc = f >> 4;
    int r4 = (f & 15) << 2;
    ushort4 o;
    o.x = t[cc][r4 + 0];
    o.y = t[cc][r4 + 1];
    o.z = t[cc][r4 + 2];
    o.w = t[cc][r4 + 3];
    *(ushort4*)(outp + (size_t)(c0 + cc) * R + r0 + r4) = o;
  }
}

// ---------------------------------------------------------------------------
// 128xBN x64 MFMA GEMM, global_load_lds staging. WN=4 -> BN=128 (proven
// path); WN=2 -> BN=64 for small-N GEMMs (2x block count).
// EPI 0: QKV scatter (K/V to fragment-major), flat 1280-block active grid;
// EPI 1: R scatter (frag-major); EPI 2: bias/resid/relu -> f32/bf16.
// Fragment-major layout (per 64-row slab, stride 131072 shorts):
//   AC/BD-type: idx = (t16*2+half)*512 + (quad*16+l15)*8 + e
//               value = X[row=t16*16+l15][col=half*32+quad*8+e]
//   PV-type V:  idx = jt*8192 + (ks*4+nto)*512 + (quad*16+l15)*8 + e
//               value = V[j=jt*128+ks*32+quad*8+e][d=nto*16+l15]
// ---------------------------------------------------------------------------
struct GemmArgs {
  const unsigned short* A;   // bf16 [M][K]
  const unsigned short* Bt;  // bf16 [N][K]
  int row_split;             // (unused; kept for ABI stability)
  int M, N, K;
  const float* p0;  // bias_q (EPI0) / bias (EPI2)
  const float* p1;  // bias_k (EPI0)
  const float* resid;
  float* outF;
  unsigned short* o0;  // QQ / Rf / bf16-out
  unsigned short* o1;  // QK
  unsigned short* o2;  // Kf
  unsigned short* o3;  // Vf
  int relu;
};

constexpr int BM = 128, BK = 64;

template <int EPI, int WN = 4>
__global__ __launch_bounds__(256, 4) void gemm_kernel(GemmArgs ga) {
  constexpr int BN_ = WN * 32;
  __shared__ __align__(16) unsigned short As[BM * BK];
  __shared__ __align__(16) unsigned short Bs[BN_ * BK];

  int m0, n0;
  if constexpr (EPI == 0) {
    // flat enumeration of the 1280 active tiles (skip q-cols x memory-rows)
    const int flat = blockIdx.x;
    int mt_, nt_;
    if (flat < 1024) {         // K/V columns: ntile 8..23, all 64 m-tiles
      mt_ = flat >> 4;
      nt_ = 8 + (flat & 15);
    } else {                   // q columns: ntile 0..7, m-tiles 32..63
      const int f2 = flat - 1024;
      mt_ = 32 + (f2 >> 3);
      nt_ = f2 & 7;
    }
    m0 = mt_ * 128;
    n0 = nt_ * 128;
  } else {
    n0 = blockIdx.x * BN_;
    m0 = blockIdx.y * BM;
  }
  const int tid = threadIdx.x;
  const int lane = tid & 63;
  const int wv = tid >> 6;
  const int l15 = lane & 15;
  const int quad = lane >> 4;
  const int wm = wv & 1, wn = wv >> 1;
  const int K = ga.K;
  const int r8 = lane >> 3;
  const int sc = (lane & 7) ^ r8;

  const f32x4 fzero = {0.f, 0.f, 0.f, 0.f};
  f32x4 acc[4][WN];
#pragma unroll
  for (int i = 0; i < 4; ++i)
#pragma unroll
    for (int j = 0; j < WN; ++j) acc[i][j] = fzero;

  const unsigned short* Ab = ga.A + (size_t)(m0 + 32 * wv + r8) * K + sc * 8;
  const unsigned short* Bb = ga.Bt + (size_t)(n0 + (BN_ / 4) * wv + r8) * K + sc * 8;
  const int h7 = l15 & 7;

  for (int k0 = 0; k0 < K; k0 += BK) {
    __syncthreads();
#pragma unroll
    for (int it = 0; it < 4; ++it)
      load16(Ab + (size_t)(8 * it) * K + k0, &As[(32 * wv + 8 * it) * 64]);
#pragma unroll
    for (int it = 0; it < BN_ / 32; ++it)
      load16(Bb + (size_t)(8 * it) * K + k0, &Bs[((BN_ / 4) * wv + 8 * it) * 64]);
    __syncthreads();
#pragma unroll
    for (int ks = 0; ks < 2; ++ks) {
      bf16x8 af[4], bg[WN];
#pragma unroll
      for (int mt = 0; mt < 4; ++mt)
        af[mt] = *(const bf16x8*)&As[(wm * 64 + mt * 16 + l15) * 64 +
                                     (((ks * 4 + quad) ^ h7) * 8)];
#pragma unroll
      for (int nt = 0; nt < WN; ++nt)
        bg[nt] = *(const bf16x8*)&Bs[(wn * (WN * 16) + nt * 16 + l15) * 64 +
                                     (((ks * 4 + quad) ^ h7) * 8)];
#pragma unroll
      for (int mt = 0; mt < 4; ++mt)
#pragma unroll
        for (int nt = 0; nt < WN; ++nt)
          acc[mt][nt] =
              __builtin_amdgcn_mfma_f32_16x16x32_bf16(af[mt], bg[nt], acc[mt][nt], 0, 0, 0);
    }
  }

#pragma unroll
  for (int mt = 0; mt < 4; ++mt) {
#pragma unroll
    for (int nt = 0; nt < WN; ++nt) {
#pragma unroll
      for (int r = 0; r < 4; ++r) {
        const int row = m0 + wm * 64 + mt * 16 + quad * 4 + r;
        const int col = n0 + wn * (WN * 16) + nt * 16 + l15;
        float val = acc[mt][nt][r];
        if constexpr (EPI == 0) {
          const int seq = row >> 2, b = row & 3;  // cat flat row = seq*BSZ + b
          if (col < 1024) {
            if (seq >= 1024) {
              const int nh = col >> 6, d = col & 63;
              const size_t o = ((size_t)((b * 16 + nh) * 1024 + (seq - 1024))) * 64 + d;
              ga.o0[o] = f2bf(val + ga.p0[col]);  // q + bias_q
              ga.o1[o] = f2bf(val + ga.p1[col]);  // q + bias_k
            }
          } else if (col < 2048) {
            // K -> fragment-major
            const int c = col - 1024, nh = c >> 6, d = c & 63, bn = b * 16 + nh;
            const size_t o = (size_t)bn * 131072 +
                             (size_t)(((seq >> 4) * 2 + (d >> 5)) * 512) +
                             ((((d >> 3) & 3) * 16 + (seq & 15)) * 8) + (d & 7);
            ga.o2[o] = f2bf(val);
          } else {
            // V -> fragment-major (PV-type)
            const int c = col - 2048, nh = c >> 6, d = c & 63, bn = b * 16 + nh;
            const size_t o = (size_t)bn * 131072 + (size_t)((seq >> 7) * 8192) +
                             ((((seq >> 5) & 3) * 4 + (d >> 4)) * 512) +
                             ((((seq >> 3) & 3) * 16 + (d & 15)) * 8) + (seq & 7);
            ga.o3[o] = f2bf(val);
          }
        } else if constexpr (EPI == 1) {
          // R -> fragment-major per head
          const int nh = col >> 6, d = col & 63, t = row;
          const size_t o = (size_t)nh * 131072 +
                           (size_t)(((t >> 4) * 2 + (d >> 5)) * 512) +
                           ((((d >> 3) & 3) * 16 + (t & 15)) * 8) + (d & 7);
          ga.o0[o] = f2bf(val);
        } else {
          if (ga.p0) val += ga.p0[col];
          if (ga.resid) val += ga.resid[(size_t)row * ga.N + col];
          if (ga.relu) val = fmaxf(val, 0.f);
          if (ga.outF) ga.outF[(size_t)row * ga.N + col] = val;
          if (ga.o0) ga.o0[(size_t)row * ga.N + col] = f2bf(val);
        }
      }
    }
  }
}

// ---------------------------------------------------------------------------
// Flash attention with Transformer-XL relative-position term (v6, round-0
// byte-exact). Barrier-free; one wave per 16-row i-tile; 4 blocks/CU. All
// K/V/R B-operands are coalesced dwordx4 loads from fragment-major global
// slabs (L2-resident; block%8 == bn%8 keeps each XCD at 8 slabs). The 4
// waves of a block scan the same j-chunks in lockstep -> L1 line sharing.
// Fixed-max softmax; l reduced once at epilogue; P hop via wave-private LDS.
// ---------------------------------------------------------------------------
constexpr int P_LD = 136;            // p_s row stride (bf16 elems)
constexpr float CEXP = 0.18033688f;  // 0.125 * log2(e)

__global__ __launch_bounds__(256, 4) void attn_kernel(
    const unsigned short* __restrict__ QQ, const unsigned short* __restrict__ QK,
    const unsigned short* __restrict__ Kf, const unsigned short* __restrict__ Vf,
    const unsigned short* __restrict__ Rf, unsigned short* __restrict__ AVb) {
  __shared__ __align__(16) unsigned short p_s[4][16 * P_LD];

  const int tid = threadIdx.x;
  const int lane = tid & 63;
  const int wv = tid >> 6;
  const int l15 = lane & 15;
  const int quad = lane >> 4;
  const int bn = blockIdx.x;                   // (b,n): block%8 == bn%8 -> XCD locality
  const int iw = (blockIdx.y * 4 + wv) * 16;   // wave-private 16-row i-tile
  const int nh = bn & 15;
  const int bb = bn >> 4;
  unsigned short* pw = &p_s[wv][0];

  const unsigned short* kf = Kf + (size_t)bn * 131072;
  const unsigned short* vf = Vf + (size_t)bn * 131072;
  const unsigned short* rf = Rf + (size_t)nh * 131072;

  // Q fragments in registers: rows [iw, iw+16)
  const size_t qoff = (size_t)bn * (1024 * 64) + (size_t)(iw + l15) * 64;
  const bf16x8 qq0 = *(const bf16x8*)(QQ + qoff + quad * 8);
  const bf16x8 qq1 = *(const bf16x8*)(QQ + qoff + 32 + quad * 8);
  const bf16x8 qk0 = *(const bf16x8*)(QK + qoff + quad * 8);
  const bf16x8 qk1 = *(const bf16x8*)(QK + qoff + 32 + quad * 8);

  const f32x4 fzero = {0.f, 0.f, 0.f, 0.f};
  f32x4 o_acc[4];
#pragma unroll
  for (int i = 0; i < 4; ++i) o_acc[i] = fzero;
  float lsum[4] = {0.f, 0.f, 0.f, 0.f};

  const int lane8 = lane * 8;
  const int jmax = iw + 15 + 1024;  // beyond this, tiles are fully masked
  for (int j0 = 0; j0 <= jmax; j0 += 128) {
    // BDu: window base t16b = (j0 + 1008 - iw)/16; 9 fragment tiles, clamped
    const int t16b = (j0 >> 4) + 63 - (iw >> 4);
    f32x4 bd[9];
#pragma unroll
    for (int ct = 0; ct < 9; ++ct) {
      int tg = t16b + ct;
      tg = (tg < 127) ? tg : 127;  // rows >=2048 only feed masked cols
      const unsigned short* rb = rf + (size_t)(tg * 1024) + lane8;
      bf16x8 b0 = *(const bf16x8*)rb;
      bf16x8 b1 = *(const bf16x8*)(rb + 512);
      f32x4 c = fzero;
      c = __builtin_amdgcn_mfma_f32_16x16x32_bf16(qk0, b0, c, 0, 0, 0);
      c = __builtin_amdgcn_mfma_f32_16x16x32_bf16(qk1, b1, c, 0, 0, 0);
      bd[ct] = c;
    }

    // AC = (q+bias_q) @ K^T
    const int ntb = j0 >> 4;
    f32x4 sv[8];
#pragma unroll
    for (int nt = 0; nt < 8; ++nt) {
      const unsigned short* kb = kf + (size_t)((ntb + nt) * 1024) + lane8;
      bf16x8 b0 = *(const bf16x8*)kb;
      bf16x8 b1 = *(const bf16x8*)(kb + 512);
      f32x4 c = fzero;
      c = __builtin_amdgcn_mfma_f32_16x16x32_bf16(qq0, b0, c, 0, 0, 0);
      c = __builtin_amdgcn_mfma_f32_16x16x32_bf16(qq1, b1, c, 0, 0, 0);
      sv[nt] = c;
    }

    // rel-shift (in-quad rotate) + fixed-max exp + per-lane l accumulation
#pragma unroll
    for (int r = 0; r < 4; ++r) {
      const int il = quad * 4 + r;  // tile-local row
      const int u = l15 + 15 - il;  // 0..30
      const int srcl = (lane & 48) | (u & 15);
      float w[9];
#pragma unroll
      for (int ct = 0; ct < 9; ++ct) w[ct] = __shfl(bd[ct][r], srcl, 64);
      const int ig = iw + il;
#pragma unroll
      for (int nt = 0; nt < 8; ++nt) {
        const float bdv = (u & 16) ? w[nt + 1] : w[nt];
        const int jg = j0 + nt * 16 + l15;
        float p = exp2f((sv[nt][r] + bdv) * CEXP);
        p = (jg > ig + 1024) ? 0.f : p;  // select: garbage/NaN-safe
        lsum[r] += p;
        pw[il * P_LD + nt * 16 + l15] = f2bf(p);
      }
    }

    // O += P @ V (K-dim = 128); V fragments coalesced from global
    const unsigned short* vb = vf + (size_t)((j0 >> 7) * 8192) + lane8;
#pragma unroll
    for (int ks = 0; ks < 4; ++ks) {
      bf16x8 ap = *(const bf16x8*)&pw[l15 * P_LD + ks * 32 + quad * 8];
#pragma unroll
      for (int nto = 0; nto < 4; ++nto) {
        bf16x8 bv = *(const bf16x8*)(vb + (ks * 4 + nto) * 512);
        o_acc[nto] = __builtin_amdgcn_mfma_f32_16x16x32_bf16(ap, bv, o_acc[nto], 0, 0, 0);
      }
    }
  }

  // reduce l across the 16 lanes holding each row, then write O/l
  float linv[4];
#pragma unroll
  for (int r = 0; r < 4; ++r) {
    float l = lsum[r];
    l += __shfl_xor(l, 1, 64);
    l += __shfl_xor(l, 2, 64);
    l += __shfl_xor(l, 4, 64);
    l += __shfl_xor(l, 8, 64);
    linv[r] = 1.f / l;
  }
#pragma unroll
  for (int nto = 0; nto < 4; ++nto) {
#pragma unroll
    for (int r = 0; r < 4; ++r) {
      const int ig = iw + quad * 4 + r;
      const int d = nto * 16 + l15;
      const float val = o_acc[nto][r] * linv[r];
      AVb[(size_t)(ig * 4 + bb) * 1024 + nh * 64 + d] = f2bf(val);
    }
  }
}

// ---------------------------------------------------------------------------
// LayerNorm over rows of 1024; optional f32 and bf16 outputs.
// ---------------------------------------------------------------------------
__global__ __launch_bounds__(256) void ln_kernel(const float* __restrict__ x,
                                                 const float* __restrict__ g,
                                                 const float* __restrict__ bta,
                                                 float* __restrict__ outF,
                                                 unsigned short* __restrict__ outB) {
  const int row = blockIdx.x;
  const int tid = threadIdx.x;
  const float* xr = x + (size_t)row * 1024;
  const float4 v = *(const float4*)(xr + tid * 4);
  float s = v.x + v.y + v.z + v.w;
  float ss = v.x * v.x + v.y * v.y + v.z * v.z + v.w * v.w;
#pragma unroll
  for (int off = 1; off < 64; off <<= 1) {
    s += __shfl_xor(s, off, 64);
    ss += __shfl_xor(ss, off, 64);
  }
  __shared__ float red[8];
  const int wv = tid >> 6;
  if ((tid & 63) == 0) {
    red[wv] = s;
    red[4 + wv] = ss;
  }
  __syncthreads();
  s = red[0] + red[1] + red[2] + red[3];
  ss = red[4] + red[5] + red[6] + red[7];
  const float mu = s * (1.f / 1024.f);
  const float var = ss * (1.f / 1024.f) - mu * mu;
  const float rs = rsqrtf(var + 1e-5f);
  const float vv[4] = {v.x, v.y, v.z, v.w};
#pragma unroll
  for (int u = 0; u < 4; ++u) {
    const int c = tid * 4 + u;
    const float y = (vv[u] - mu) * rs * g[c] + bta[c];
    if (outF) outF[(size_t)row * 1024 + c] = y;
    if (outB) outB[(size_t)row * 1024 + c] = f2bf(y);
  }
}

// ---------------------------------------------------------------------------
extern "C" void kernel_launch(void* const* d_in, const int* in_sizes, int n_in,
                              void* d_out, int out_size, void* d_ws, size_t ws_size,
                              hipStream_t stream) {
  (void)in_sizes; (void)n_in; (void)out_size; (void)ws_size;
  const float* word_embed = (const float*)d_in[0];
  const float* pos_embed = (const float*)d_in[1];
  const float* bias_q = (const float*)d_in[2];
  const float* bias_k = (const float*)d_in[3];
  const float* memories = (const float*)d_in[4];
  const float* W_qkv = (const float*)d_in[5];
  const float* W_r = (const float*)d_in[6];
  const float* W_o = (const float*)d_in[7];
  const float* ln1_g = (const float*)d_in[8];
  const float* ln1_b = (const float*)d_in[9];
  const float* W_ff1 = (const float*)d_in[10];
  const float* b_ff1 = (const float*)d_in[11];
  const float* W_ff2 = (const float*)d_in[12];
  const float* b_ff2 = (const float*)d_in[13];
  const float* ln2_g = (const float*)d_in[14];
  const float* ln2_b = (const float*)d_in[15];
  float* out = (float*)d_out;

  char* ws = (char*)d_ws;
  unsigned short* QQ = (unsigned short*)(ws + 0);           // 8 MB
  unsigned short* QK = (unsigned short*)(ws + 8388608);     // 8 MB
  unsigned short* Kf = (unsigned short*)(ws + 16777216);    // 16 MB (frag-major)
  unsigned short* Vf = (unsigned short*)(ws + 50331648);    // 16 MB (frag-major)
  unsigned short* Rf = (unsigned short*)(ws + 67108864);    // 4 MB (frag-major)
  unsigned short* AVb = (unsigned short*)(ws + 71303168);   // 8 MB
  float* X1 = (float*)(ws + 79691776);                      // 16 MB (also C2)
  float* OUT1 = (float*)(ws + 96468992);                    // 16 MB
  unsigned short* OUT1b = (unsigned short*)(ws + 113246208);  // 8 MB
  unsigned short* Wqkv_t = (unsigned short*)(ws + 121634816); // 6 MB
  unsigned short* Wr_t = (unsigned short*)(ws + 127926272);   // 2 MB
  unsigned short* Wo_t = (unsigned short*)(ws + 130023424);   // 2 MB
  unsigned short* Wff1_t = (unsigned short*)(ws + 132120576); // 8 MB
  unsigned short* Wff2_t = (unsigned short*)(ws + 140509184); // 8 MB
  unsigned short* Catb = (unsigned short*)(ws + 79691776);    // aliases X1
  unsigned short* Posb = (unsigned short*)(ws + 96468992);    // aliases OUT1
  unsigned short* H = (unsigned short*)(ws + 0);              // aliases QQ/QK/Kf
  float* C2 = X1;

  const dim3 blk(256);

  cvt_bf16_kernel<<<4096, blk, 0, stream>>>(memories, Catb);
  cvt_bf16_kernel<<<4096, blk, 0, stream>>>(word_embed, Catb + (size_t)4096 * 1024);
  cvt_bf16_kernel<<<2048, blk, 0, stream>>>(pos_embed, Posb);

  transpose_to_bf16<float><<<dim3(48, 16, 1), blk, 0, stream>>>(W_qkv, Wqkv_t, 1024, 3072);
  transpose_to_bf16<float><<<dim3(16, 16, 1), blk, 0, stream>>>(W_r, Wr_t, 1024, 1024);
  transpose_to_bf16<float><<<dim3(16, 16, 1), blk, 0, stream>>>(W_o, Wo_t, 1024, 1024);
  transpose_to_bf16<float><<<dim3(64, 16, 1), blk, 0, stream>>>(W_ff1, Wff1_t, 1024, 4096);
  transpose_to_bf16<float><<<dim3(16, 64, 1), blk, 0, stream>>>(W_ff2, Wff2_t, 4096, 1024);

  // QKV projection: M=8192, N=3072, K=1024; flat 1280-block active grid
  {
    GemmArgs a{};
    a.A = Catb;
    a.Bt = Wqkv_t;
    a.M = 8192; a.N = 3072; a.K = 1024;
    a.p0 = bias_q; a.p1 = bias_k;
    a.o0 = QQ; a.o1 = QK; a.o2 = Kf; a.o3 = Vf;
    gemm_kernel<0><<<dim3(1280), blk, 0, stream>>>(a);
  }
  // R projection: M=2048, N=1024, K=1024 -> fragment-major per head (BN=64)
  {
    GemmArgs a{};
    a.A = Posb;
    a.Bt = Wr_t;
    a.M = 2048; a.N = 1024; a.K = 1024;
    a.o0 = Rf;
    gemm_kernel<1, 2><<<dim3(16, 16), blk, 0, stream>>>(a);
  }

  // attention: grid (bn=64, itile=16), 1024 blocks, 4/CU, barrier-free
  attn_kernel<<<dim3(64, 16), blk, 0, stream>>>(QQ, QK, Kf, Vf, Rf, AVb);

  // W_o projection (BN=64 -> 512 blocks, 2/CU)
  {
    GemmArgs a{};
    a.A = AVb;
    a.Bt = Wo_t;
    a.M = 4096; a.N = 1024; a.K = 1024;
    a.resid = word_embed;
    a.outF = X1;
    gemm_kernel<2, 2><<<dim3(16, 32), blk, 0, stream>>>(a);
  }
  ln_kernel<<<4096, blk, 0, stream>>>(X1, ln1_g, ln1_b, OUT1, OUT1b);

  // FF1 (BN=128, 1024 blocks)
  {
    GemmArgs a{};
    a.A = OUT1b;
    a.Bt = Wff1_t;
    a.M = 4096; a.N = 4096; a.K = 1024;
    a.p0 = b_ff1;
    a.relu = 1;
    a.o0 = H;
    gemm_kernel<2><<<dim3(32, 32), blk, 0, stream>>>(a);
  }
  // FF2 (BN=64 -> 512 blocks, 2/CU)
  {
    GemmArgs a{};
    a.A = H;
    a.Bt = Wff2_t;
    a.M = 4096; a.N = 1024; a.K = 4096;
    a.p0 = b_ff2;
    a.resid = OUT1;
    a.outF = C2;
    gemm_kernel<2, 2><<<dim3(16, 32), blk, 0, stream>>>(a);
  }
  ln_kernel<<<4096, blk, 0, stream>>>(C2, ln2_g, ln2_b, out, nullptr);
}